// Round 1
// baseline (1122.493 us; speedup 1.0000x reference)
//
#include <hip/hip_runtime.h>
#include <cstdint>
#include <cstddef>

// ---------------------------------------------------------------------------
// Optical-flow estimator head, MI355X bf16 MFMA implementation.
//
// Pipeline:
//   prep kernels : repack w1..w6 (OIHW f32) -> bf16 [tap][co][ci] (padded)
//   corr_kernel  : 81-tap windowed correlation (f32, LDS-tiled) -> X1 ch 164..244 (lrelu'd)
//   concat_kernel: feat0|feat1|last_feat|last_flow (NCHW f32) -> X1 ch 0..163 (NHWC bf16)
//   conv_kernel  : implicit-GEMM 16x16x32 bf16 MFMA, taps as shifted GEMMs
//
// X layout: NHWC bf16, [pix = b*65536 + h*256 + w][C_stride]
// conv1 K-order permuted: X1 = [feats 0..163 | volume 164..244 | zero 245..255],
// w1p permuted to match.
// Workspace: region A @0 (X1/X3/X5), region B @ elem 33554432 (X2/X4/X6),
// weights @ elem 54525952. Total ~105 MB.
// ---------------------------------------------------------------------------

using short8 = __attribute__((ext_vector_type(8))) short;
using f32x4  = __attribute__((ext_vector_type(4))) float;
typedef unsigned short u16;

__device__ __forceinline__ u16 rne_bf16(float f) {
  unsigned u = __float_as_uint(f);
  u += 0x7FFFu + ((u >> 16) & 1u);   // round-to-nearest-even
  return (u16)(u >> 16);
}

// D = A*B + C, D==C tied. A rows = weights (M=co), B cols = pixels (N).
__device__ __forceinline__ void mfma16(const short8& a, const short8& b, f32x4& c) {
  asm("v_mfma_f32_16x16x32_bf16 %0, %1, %2, %0" : "+v"(c) : "v"(a), "v"(b));
}

// ---------------------------------------------------------------------------
// Weight prep
// ---------------------------------------------------------------------------

// w1 [160][245] f32 -> w1p [160][256] bf16 with K-permutation:
// cip < 164 -> orig ci = cip + 81 (feats); 164..244 -> cip - 164 (volume); else 0.
__global__ __launch_bounds__(256) void prep1_kernel(const float* __restrict__ w1,
                                                    u16* __restrict__ w1p) {
  int idx = blockIdx.x * 256 + threadIdx.x;     // < 160*256
  int co = idx >> 8, cip = idx & 255;
  float v = 0.f;
  if (cip < 245) {
    int ci = (cip < 164) ? (cip + 81) : (cip - 164);
    v = w1[co * 245 + ci];
  }
  w1p[idx] = rne_bf16(v);
}

// w [CO][CI][3][3] f32 -> wp [9][COP][CIP] bf16 (zero-padded)
template<int CO, int CI, int COP, int CIP>
__global__ __launch_bounds__(256) void prep3_kernel(const float* __restrict__ w,
                                                    u16* __restrict__ wp) {
  int idx = blockIdx.x * 256 + threadIdx.x;     // < 9*COP*CIP
  int ci = idx % CIP; int rest = idx / CIP;
  int co = rest % COP; int tap = rest / COP;
  float v = 0.f;
  if (co < CO && ci < CI) v = w[(co * CI + ci) * 9 + tap];
  wp[idx] = rne_bf16(v);
}

// ---------------------------------------------------------------------------
// Correlation: cv[b, dy*9+dx, h, w] = lrelu(mean_c f0[c,h,w]*f1[c,h+dy-4,w+dx-4])
// -> X1 channels 164..244 (245..255 zeroed). Block = one row (256 px).
// LDS window: [3 ch-pairs][9 rows][264 cols][2 ch] f32 = 57 KB, 8 chunks of 6 ch.
// ---------------------------------------------------------------------------
__global__ __launch_bounds__(256) void corr_kernel(const float* __restrict__ f0,
                                                   const float* __restrict__ f1,
                                                   u16* __restrict__ X1) {
  const int b = blockIdx.x >> 8;
  const int h = blockIdx.x & 255;
  const int w = threadIdx.x;
  __shared__ float s1[3 * 9 * 264 * 2];
  float cv[81];
#pragma unroll
  for (int t = 0; t < 81; ++t) cv[t] = 0.f;

#pragma unroll 1
  for (int chunk = 0; chunk < 8; ++chunk) {
    __syncthreads();
    for (int t = threadIdx.x; t < 3 * 9 * 264 * 2; t += 256) {
      int c01 = t & 1; int rest = t >> 1;
      int col = rest % 264; int q = rest / 264;
      int r = q % 9; int p = q / 9;
      int hin = h + r - 4, win = col - 4;
      int ch = chunk * 6 + p * 2 + c01;
      float v = 0.f;
      if ((unsigned)hin < 256u && (unsigned)win < 256u)
        v = f1[(((size_t)(b * 48 + ch)) << 16) + (hin << 8) + win];
      s1[t] = v;
    }
    __syncthreads();
    float a0[6];
#pragma unroll
    for (int j = 0; j < 6; ++j)
      a0[j] = f0[(((size_t)(b * 48 + chunk * 6 + j)) << 16) + (h << 8) + w];
#pragma unroll
    for (int dy = 0; dy < 9; ++dy) {
#pragma unroll
      for (int dx = 0; dx < 9; ++dx) {
        float sum = 0.f;
#pragma unroll
        for (int p = 0; p < 3; ++p) {
          const float2 vv = *(const float2*)&s1[(((p * 9 + dy) * 264) + w + dx) * 2];
          sum += a0[p * 2] * vv.x + a0[p * 2 + 1] * vv.y;
        }
        cv[dy * 9 + dx] += sum;
      }
    }
  }

  u16* dst = X1 + ((size_t)blockIdx.x * 256 + w) * 256 + 164;  // byte ofs %8 == 0
#pragma unroll
  for (int qq = 0; qq < 23; ++qq) {
    u16 e[4];
#pragma unroll
    for (int j = 0; j < 4; ++j) {
      int t = qq * 4 + j;
      float v = 0.f;
      if (t < 81) {
        v = cv[t] * (1.0f / 48.0f);
        v = v > 0.f ? v : 0.1f * v;   // leaky relu
      }
      e[j] = rne_bf16(v);
    }
    uint2 u;
    u.x = (unsigned)e[0] | ((unsigned)e[1] << 16);
    u.y = (unsigned)e[2] | ((unsigned)e[3] << 16);
    *(uint2*)(dst + qq * 4) = u;
  }
}

// ---------------------------------------------------------------------------
// Concat: NCHW f32 sources -> X1 NHWC bf16 channels 0..163
// [feat0 0..47 | feat1 48..95 | last_feat 96..159 | last_flow 160..163]
// Block: 64 px, LDS 16x68 f32 transpose tile, 11 chunks of 16 ch.
// ---------------------------------------------------------------------------
__global__ __launch_bounds__(256) void concat_kernel(const float* __restrict__ f0,
                                                     const float* __restrict__ f1,
                                                     const float* __restrict__ lf,
                                                     const float* __restrict__ lfl,
                                                     u16* __restrict__ X1) {
  __shared__ float s[16][68];
  const int t = threadIdx.x;
  const size_t px0 = (size_t)blockIdx.x * 64;
  const int b = blockIdx.x >> 10;
  const int hw0 = (blockIdx.x & 1023) * 64;

#pragma unroll 1
  for (int cc = 0; cc < 11; ++cc) {
    __syncthreads();
    {
      int px = t & 63, cg = t >> 6;
#pragma unroll
      for (int r = 0; r < 4; ++r) {
        int cl = cg * 4 + r;            // 0..15
        int c = cc * 16 + cl;           // 0..175
        int hw = hw0 + px;
        float v = 0.f;
        if (c < 48)       v = f0[(((size_t)(b * 48 + c)) << 16) + hw];
        else if (c < 96)  v = f1[(((size_t)(b * 48 + (c - 48))) << 16) + hw];
        else if (c < 160) v = lf[(((size_t)(b * 64 + (c - 96))) << 16) + hw];
        else if (c < 164) v = lfl[(((size_t)(b * 4 + (c - 160))) << 16) + hw];
        s[cl][px] = v;
      }
    }
    __syncthreads();
    {
      int px = t >> 2, g = t & 3;
      int cbase = cc * 16 + g * 4;
      if (cbase < 164) {                 // cc=10: only g=0 (ch 160..163)
        ushort4 u;
        u.x = rne_bf16(s[g * 4 + 0][px]);
        u.y = rne_bf16(s[g * 4 + 1][px]);
        u.z = rne_bf16(s[g * 4 + 2][px]);
        u.w = rne_bf16(s[g * 4 + 3][px]);
        *(ushort4*)(X1 + (px0 + px) * 256 + cbase) = u;
      }
    }
  }
}

// ---------------------------------------------------------------------------
// Implicit-GEMM conv. Tile: BM = MF*16 output channels x BN = 128 px (half row).
// 4 waves, each 32 px (2 n-frags). 3x3 = 9 shifted GEMMs, per-lane col predication.
// CI = padded input channel stride; COP = padded CO (weight row count).
// OBF: write NHWC bf16 (stride ostride); COF32>0: also/only write NCHW f32.
// ---------------------------------------------------------------------------
template<int CI, int COP, int MF, int KS, bool LRELU, bool OBF, int COF32>
__global__ __launch_bounds__(256) void conv_kernel(const u16* __restrict__ Xin,
                                                   const u16* __restrict__ Wp,
                                                   const float* __restrict__ bias,
                                                   u16* __restrict__ Xout, int ostride,
                                                   float* __restrict__ outF) {
  const int lane = threadIdx.x & 63, wv = threadIdx.x >> 6;
  const int bi = blockIdx.x >> 9;
  const int h = (blockIdx.x >> 1) & 255;
  const int w0 = (blockIdx.x & 1) << 7;
  const int co0 = blockIdx.y * (MF * 16);
  const int l15 = lane & 15, klane = (lane >> 4) << 3;
  const int ncol0 = w0 + wv * 32 + l15;
  const int rowbase = (bi << 8) + h;

  const f32x4 zf = {0.f, 0.f, 0.f, 0.f};
  const short8 z8 = {0, 0, 0, 0, 0, 0, 0, 0};
  f32x4 acc[MF][2];
#pragma unroll
  for (int m = 0; m < MF; ++m) { acc[m][0] = zf; acc[m][1] = zf; }

#pragma unroll 1
  for (int chunk = 0; chunk < CI / 32; ++chunk) {
#pragma unroll
    for (int tap = 0; tap < KS * KS; ++tap) {
      const int dy = (KS == 3) ? tap / 3 - 1 : 0;
      const int dx = (KS == 3) ? tap % 3 - 1 : 0;
      const int hin = h + dy;
      if (KS == 3 && (unsigned)hin >= 256u) continue;   // row OOB: tap contributes 0
      short8 bf[2];
#pragma unroll
      for (int nf = 0; nf < 2; ++nf) {
        int win = ncol0 + nf * 16 + dx;
        short8 v = z8;
        if (KS == 1 || (unsigned)win < 256u)
          v = *(const short8*)(Xin + ((size_t)(((bi << 8) + hin) * 256 + win)) * CI
                               + chunk * 32 + klane);
        bf[nf] = v;
      }
#pragma unroll
      for (int m = 0; m < MF; ++m) {
        const short8 af = *(const short8*)(Wp + ((size_t)(tap * COP + co0 + m * 16 + l15)) * CI
                                           + chunk * 32 + klane);
        mfma16(af, bf[0], acc[m][0]);
        mfma16(af, bf[1], acc[m][1]);
      }
    }
  }
  asm volatile("s_nop 7\n\ts_nop 7");   // MFMA -> VALU read hazard insurance

  const int co_sub = (lane >> 4) << 2;
  const size_t pixrow = (size_t)rowbase << 8;
#pragma unroll
  for (int m = 0; m < MF; ++m) {
    const int co = co0 + m * 16 + co_sub;
#pragma unroll
    for (int nf = 0; nf < 2; ++nf) {
      const int w = ncol0 + nf * 16;
      f32x4 v = acc[m][nf];
      if constexpr (OBF) {
        float t[4];
#pragma unroll
        for (int r = 0; r < 4; ++r) {
          float x = v[r] + bias[co + r];
          if constexpr (LRELU) x = x > 0.f ? x : 0.1f * x;
          t[r] = x;
        }
        ushort4 u;
        u.x = rne_bf16(t[0]); u.y = rne_bf16(t[1]);
        u.z = rne_bf16(t[2]); u.w = rne_bf16(t[3]);
        *(ushort4*)(Xout + (pixrow + w) * (size_t)ostride + co) = u;
      }
      if constexpr (COF32 > 0) {
#pragma unroll
        for (int r = 0; r < 4; ++r) {
          int c = co + r;
          if (c < COF32) {
            float x = v[r] + bias[c];
            if constexpr (LRELU) x = x > 0.f ? x : 0.1f * x;
            outF[((((size_t)bi * COF32) + c) << 16) + (h << 8) + w] = x;
          }
        }
      }
    }
  }
}

// ---------------------------------------------------------------------------
extern "C" void kernel_launch(void* const* d_in, const int* in_sizes, int n_in,
                              void* d_out, int out_size, void* d_ws, size_t ws_size,
                              hipStream_t stream) {
  const float* feat0 = (const float*)d_in[0];
  const float* feat1 = (const float*)d_in[1];
  const float* lfeat = (const float*)d_in[2];
  const float* lflow = (const float*)d_in[3];
  const float* w1 = (const float*)d_in[4];  const float* b1 = (const float*)d_in[5];
  const float* w2 = (const float*)d_in[6];  const float* b2 = (const float*)d_in[7];
  const float* w3 = (const float*)d_in[8];  const float* b3 = (const float*)d_in[9];
  const float* w4 = (const float*)d_in[10]; const float* b4 = (const float*)d_in[11];
  const float* w5 = (const float*)d_in[12]; const float* b5 = (const float*)d_in[13];
  const float* w6 = (const float*)d_in[14]; const float* b6 = (const float*)d_in[15];

  u16* ws = (u16*)d_ws;
  // Region A (elem 0): X1 [131072][256] -> X3 [131072][128] -> X5 [131072][96]
  // Region B (elem 33554432): X2 [131072][160] -> X4 [131072][128] -> X6 [131072][64]
  u16* X1 = ws;
  u16* X2 = ws + 33554432;
  u16* X3 = ws;
  u16* X4 = ws + 33554432;
  u16* X5 = ws;
  u16* X6 = ws + 33554432;
  u16* w1p = ws + 54525952;      // [160][256]
  u16* w2p = w1p + 40960;        // [9][128][160]
  u16* w3p = w2p + 184320;       // [9][112][128]
  u16* w4p = w3p + 129024;       // [9][96][128] (ci 112..127 zero)
  u16* w5p = w4p + 110592;       // [9][64][96]
  u16* w6p = w5p + 55296;        // [9][16][64]  (co 4..15 zero)

  float* flow = (float*)d_out;              // [2][4][256][256]
  float* xout = (float*)d_out + 524288;     // [2][64][256][256]

  prep1_kernel<<<160, 256, 0, stream>>>(w1, w1p);
  prep3_kernel<128, 160, 128, 160><<<720, 256, 0, stream>>>(w2, w2p);
  prep3_kernel<112, 128, 112, 128><<<504, 256, 0, stream>>>(w3, w3p);
  prep3_kernel< 96, 112,  96, 128><<<432, 256, 0, stream>>>(w4, w4p);
  prep3_kernel< 64,  96,  64,  96><<<216, 256, 0, stream>>>(w5, w5p);
  prep3_kernel<  4,  64,  16,  64><<< 36, 256, 0, stream>>>(w6, w6p);

  corr_kernel<<<512, 256, 0, stream>>>(feat0, feat1, X1);
  concat_kernel<<<2048, 256, 0, stream>>>(feat0, feat1, lfeat, lflow, X1);

  // <CI, COP, MF, KS, LRELU, OBF, COF32>
  conv_kernel<256, 160, 5, 1, true,  true,  0><<<dim3(1024, 2), 256, 0, stream>>>(X1, w1p, b1, X2, 160, nullptr);
  conv_kernel<160, 128, 8, 3, true,  true,  0><<<dim3(1024, 1), 256, 0, stream>>>(X2, w2p, b2, X3, 128, nullptr);
  conv_kernel<128, 112, 7, 3, true,  true,  0><<<dim3(1024, 1), 256, 0, stream>>>(X3, w3p, b3, X4, 128, nullptr);
  conv_kernel<128,  96, 6, 3, true,  true,  0><<<dim3(1024, 1), 256, 0, stream>>>(X4, w4p, b4, X5,  96, nullptr);
  conv_kernel< 96,  64, 4, 3, true,  true, 64><<<dim3(1024, 1), 256, 0, stream>>>(X5, w5p, b5, X6,  64, xout);
  conv_kernel< 64,  16, 1, 3, false, false, 4><<<dim3(1024, 1), 256, 0, stream>>>(X6, w6p, b6, nullptr, 0, flow);
}

// Round 2
// 518.759 us; speedup vs baseline: 2.1638x; 2.1638x over previous
//
#include <hip/hip_runtime.h>
#include <cstdint>
#include <cstddef>

// ---------------------------------------------------------------------------
// Optical-flow estimator head, MI355X bf16 MFMA implementation. Round 2:
// LDS-staged implicit-GEMM convs (m97-style 2-barrier K-step, global_load_lds
// width 16, per-lane gather sources, 2m x 2n wave split).
//
// X layout: NHWC bf16, [pix = b*65536 + h*256 + w][C_stride]
// conv1 K-order permuted: X1 = [feats 0..163 | volume 164..244 | zero 245..255]
// Weights repacked to [tap][ASTAGE_co][CI] bf16, co/ci zero-padded.
// ---------------------------------------------------------------------------

using short8 = __attribute__((ext_vector_type(8))) short;
using f32x4  = __attribute__((ext_vector_type(4))) float;
typedef unsigned short u16;

__device__ __forceinline__ u16 rne_bf16(float f) {
  unsigned u = __float_as_uint(f);
  u += 0x7FFFu + ((u >> 16) & 1u);   // round-to-nearest-even
  return (u16)(u >> 16);
}

__device__ __forceinline__ void mfma16(const short8& a, const short8& b, f32x4& c) {
  asm("v_mfma_f32_16x16x32_bf16 %0, %1, %2, %0" : "+v"(c) : "v"(a), "v"(b));
}

// async global -> LDS, 16B per lane. LDS dest must be wave-uniform base;
// global src is per-lane (gather allowed).
__device__ __forceinline__ void gload16(const void* g, void* l) {
  __builtin_amdgcn_global_load_lds(
      (const __attribute__((address_space(1))) unsigned int*)g,
      (__attribute__((address_space(3))) unsigned int*)l, 16, 0, 0);
}

// ---------------------------------------------------------------------------
// Weight prep
// ---------------------------------------------------------------------------

// w1 [160][245] f32 -> w1p [192][256] bf16 (rows 160..191 zero) with K-perm:
// cip < 164 -> orig ci = cip + 81 (feats); 164..244 -> cip - 164 (volume); else 0.
__global__ __launch_bounds__(256) void prep1_kernel(const float* __restrict__ w1,
                                                    u16* __restrict__ w1p) {
  int idx = blockIdx.x * 256 + threadIdx.x;     // < 192*256
  int co = idx >> 8, cip = idx & 255;
  float v = 0.f;
  if (co < 160 && cip < 245) {
    int ci = (cip < 164) ? (cip + 81) : (cip - 164);
    v = w1[co * 245 + ci];
  }
  w1p[idx] = rne_bf16(v);
}

// w [CO][CI][3][3] f32 -> wp [9][COP][CIP] bf16 (zero-padded)
template<int CO, int CI, int COP, int CIP>
__global__ __launch_bounds__(256) void prep3_kernel(const float* __restrict__ w,
                                                    u16* __restrict__ wp) {
  int idx = blockIdx.x * 256 + threadIdx.x;     // < 9*COP*CIP
  int ci = idx % CIP; int rest = idx / CIP;
  int co = rest % COP; int tap = rest / COP;
  float v = 0.f;
  if (co < CO && ci < CI) v = w[(co * CI + ci) * 9 + tap];
  wp[idx] = rne_bf16(v);
}

// padded biases: bp = [b1(160) | b2(128) | b3 pad 128 | b4(96) | b5(64)], zbuf zeroed
__global__ __launch_bounds__(256) void prep_bias_kernel(const float* __restrict__ b1,
    const float* __restrict__ b2, const float* __restrict__ b3,
    const float* __restrict__ b4, const float* __restrict__ b5,
    float* __restrict__ bp, u16* __restrict__ zbuf) {
  int i = blockIdx.x * 256 + threadIdx.x;       // grid 3 blocks
  if (i < 128) zbuf[i] = 0;
  float v = 0.f;
  if (i < 160) v = b1[i];
  else if (i < 288) v = b2[i - 160];
  else if (i < 416) { int c = i - 288; v = (c < 112) ? b3[c] : 0.f; }
  else if (i < 512) v = b4[i - 416];
  else if (i < 576) v = b5[i - 512];
  else return;
  bp[i] = v;
}

// ---------------------------------------------------------------------------
// Correlation: cv[b, dy*9+dx, h, w] = lrelu(mean_c f0[c,h,w]*f1[c,h+dy-4,w+dx-4])
// -> X1 channels 164..244 (245..255 zeroed). Block = one row (256 px).
// ---------------------------------------------------------------------------
__global__ __launch_bounds__(256) void corr_kernel(const float* __restrict__ f0,
                                                   const float* __restrict__ f1,
                                                   u16* __restrict__ X1) {
  const int b = blockIdx.x >> 8;
  const int h = blockIdx.x & 255;
  const int w = threadIdx.x;
  __shared__ float s1[3 * 9 * 264 * 2];
  float cv[81];
#pragma unroll
  for (int t = 0; t < 81; ++t) cv[t] = 0.f;

#pragma unroll 1
  for (int chunk = 0; chunk < 8; ++chunk) {
    __syncthreads();
    for (int t = threadIdx.x; t < 3 * 9 * 264 * 2; t += 256) {
      int c01 = t & 1; int rest = t >> 1;
      int col = rest % 264; int q = rest / 264;
      int r = q % 9; int p = q / 9;
      int hin = h + r - 4, win = col - 4;
      int ch = chunk * 6 + p * 2 + c01;
      float v = 0.f;
      if ((unsigned)hin < 256u && (unsigned)win < 256u)
        v = f1[(((size_t)(b * 48 + ch)) << 16) + (hin << 8) + win];
      s1[t] = v;
    }
    __syncthreads();
    float a0[6];
#pragma unroll
    for (int j = 0; j < 6; ++j)
      a0[j] = f0[(((size_t)(b * 48 + chunk * 6 + j)) << 16) + (h << 8) + w];
#pragma unroll
    for (int dy = 0; dy < 9; ++dy) {
#pragma unroll
      for (int dx = 0; dx < 9; ++dx) {
        float sum = 0.f;
#pragma unroll
        for (int p = 0; p < 3; ++p) {
          const float2 vv = *(const float2*)&s1[(((p * 9 + dy) * 264) + w + dx) * 2];
          sum += a0[p * 2] * vv.x + a0[p * 2 + 1] * vv.y;
        }
        cv[dy * 9 + dx] += sum;
      }
    }
  }

  u16* dst = X1 + ((size_t)blockIdx.x * 256 + w) * 256 + 164;
#pragma unroll
  for (int qq = 0; qq < 23; ++qq) {
    u16 e[4];
#pragma unroll
    for (int j = 0; j < 4; ++j) {
      int t = qq * 4 + j;
      float v = 0.f;
      if (t < 81) {
        v = cv[t] * (1.0f / 48.0f);
        v = v > 0.f ? v : 0.1f * v;
      }
      e[j] = rne_bf16(v);
    }
    uint2 u;
    u.x = (unsigned)e[0] | ((unsigned)e[1] << 16);
    u.y = (unsigned)e[2] | ((unsigned)e[3] << 16);
    *(uint2*)(dst + qq * 4) = u;
  }
}

// ---------------------------------------------------------------------------
// Concat: NCHW f32 sources -> X1 NHWC bf16 channels 0..163
// ---------------------------------------------------------------------------
__global__ __launch_bounds__(256) void concat_kernel(const float* __restrict__ f0,
                                                     const float* __restrict__ f1,
                                                     const float* __restrict__ lf,
                                                     const float* __restrict__ lfl,
                                                     u16* __restrict__ X1) {
  __shared__ float s[16][68];
  const int t = threadIdx.x;
  const size_t px0 = (size_t)blockIdx.x * 64;
  const int b = blockIdx.x >> 10;
  const int hw0 = (blockIdx.x & 1023) * 64;

#pragma unroll 1
  for (int cc = 0; cc < 11; ++cc) {
    __syncthreads();
    {
      int px = t & 63, cg = t >> 6;
#pragma unroll
      for (int r = 0; r < 4; ++r) {
        int cl = cg * 4 + r;
        int c = cc * 16 + cl;
        int hw = hw0 + px;
        float v = 0.f;
        if (c < 48)       v = f0[(((size_t)(b * 48 + c)) << 16) + hw];
        else if (c < 96)  v = f1[(((size_t)(b * 48 + (c - 48))) << 16) + hw];
        else if (c < 160) v = lf[(((size_t)(b * 64 + (c - 96))) << 16) + hw];
        else if (c < 164) v = lfl[(((size_t)(b * 4 + (c - 160))) << 16) + hw];
        s[cl][px] = v;
      }
    }
    __syncthreads();
    {
      int px = t >> 2, g = t & 3;
      int cbase = cc * 16 + g * 4;
      if (cbase < 164) {
        ushort4 u;
        u.x = rne_bf16(s[g * 4 + 0][px]);
        u.y = rne_bf16(s[g * 4 + 1][px]);
        u.z = rne_bf16(s[g * 4 + 2][px]);
        u.w = rne_bf16(s[g * 4 + 3][px]);
        *(ushort4*)(X1 + (px0 + px) * 256 + cbase) = u;
      }
    }
  }
}

// ---------------------------------------------------------------------------
// LDS-staged implicit-GEMM conv (m97 structure).
// Tile: BM co x 128 px (half row). 4 waves, 2m x 2n. K-step = 32 ci of one tap.
// lA [ASTAGE][32] bf16, lB [128 px][32] bf16, both filled via global_load_lds
// (16B/lane, per-lane gather source). OOB columns source a zero stub (zbuf);
// OOB rows skip the whole tap.
// ---------------------------------------------------------------------------
template<int CI, int BM, int ASTAGE, int KS, int OSTRIDE, bool LRELU, bool OBF, int COF32>
__global__ __launch_bounds__(256) void convg_kernel(const u16* __restrict__ Xin,
    const u16* __restrict__ Wp, const float* __restrict__ bias,
    const u16* __restrict__ zbuf, u16* __restrict__ Xout,
    float* __restrict__ outF) {
  constexpr int MF  = BM / 32;              // m-frags per wave
  constexpr int AR  = (ASTAGE * 64) / 4096; // A staging rounds (4KB each)
  constexpr int NCH = CI / 32;
  __shared__ u16 lA[ASTAGE * 32];
  __shared__ u16 lB[128 * 32];
  const int tid  = threadIdx.x;
  const int lane = tid & 63, wv = tid >> 6;
  const int wm = wv >> 1, wn = wv & 1;
  const int bi = blockIdx.x >> 9;
  const int h  = (blockIdx.x >> 1) & 255;
  const int w0 = (blockIdx.x & 1) << 7;
  const int l15 = lane & 15, k8 = (lane >> 4) << 3;

  f32x4 acc[MF][4];
  const f32x4 zf = {0.f, 0.f, 0.f, 0.f};
#pragma unroll
  for (int m = 0; m < MF; ++m)
#pragma unroll
    for (int n = 0; n < 4; ++n) acc[m][n] = zf;

#pragma unroll 1
  for (int tap = 0; tap < KS * KS; ++tap) {
    const int dy = (KS == 3) ? tap / 3 - 1 : 0;
    const int dx = (KS == 3) ? tap % 3 - 1 : 0;
    const int hin = h + dy;
    if (KS == 3 && (unsigned)hin >= 256u) continue;  // uniform per block
    const u16* Wtap = Wp + (size_t)tap * ASTAGE * CI;
    const u16* Brow = Xin + (((size_t)((bi << 8) + hin)) << 8) * CI;

    const u16* asrc[AR];
#pragma unroll
    for (int r = 0; r < AR; ++r) {
      int idx = r * 256 + tid;
      asrc[r] = Wtap + (size_t)(idx >> 2) * CI + (idx & 3) * 8;
    }
    const u16* bsrc[2];
#pragma unroll
    for (int r = 0; r < 2; ++r) {
      int idx = r * 256 + tid;
      int px = idx >> 2, c16 = idx & 3;
      int win = w0 + dx + px;
      bsrc[r] = (KS == 1 || (unsigned)win < 256u)
                    ? (Brow + (size_t)win * CI + c16 * 8)
                    : (zbuf + c16 * 8);
    }

#pragma unroll 1
    for (int chunk = 0; chunk < NCH; ++chunk) {
      __syncthreads();   // prev step's LDS reads drained (compiler waitcnt)
#pragma unroll
      for (int r = 0; r < AR; ++r)
        gload16(asrc[r] + chunk * 32, &lA[r * 2048 + wv * 512]);
#pragma unroll
      for (int r = 0; r < 2; ++r)
        gload16(bsrc[r] + chunk * 32, &lB[r * 2048 + wv * 512]);
      __syncthreads();   // staging complete (vmcnt(0) before barrier)

      short8 af[MF], bf[4];
#pragma unroll
      for (int m = 0; m < MF; ++m)
        af[m] = *(const short8*)&lA[(wm * (BM / 2) + m * 16 + l15) * 32 + k8];
#pragma unroll
      for (int n = 0; n < 4; ++n)
        bf[n] = *(const short8*)&lB[(wn * 64 + n * 16 + l15) * 32 + k8];
#pragma unroll
      for (int m = 0; m < MF; ++m)
#pragma unroll
        for (int n = 0; n < 4; ++n) mfma16(af[m], bf[n], acc[m][n]);
    }
  }
  asm volatile("s_nop 7\n\ts_nop 7");   // MFMA -> VALU hazard insurance

  const int co_sub = (lane >> 4) << 2;
  const size_t pixbase = ((size_t)((bi << 8) + h)) << 8;
#pragma unroll
  for (int m = 0; m < MF; ++m) {
    const int co = wm * (BM / 2) + m * 16 + co_sub;
#pragma unroll
    for (int n = 0; n < 4; ++n) {
      const int px = w0 + wn * 64 + n * 16 + l15;
      f32x4 v = acc[m][n];
      float t[4];
#pragma unroll
      for (int r = 0; r < 4; ++r) {
        float x = v[r] + bias[co + r];
        if (LRELU) x = x > 0.f ? x : 0.1f * x;
        t[r] = x;
      }
      if (OBF) {
        ushort4 u;
        u.x = rne_bf16(t[0]); u.y = rne_bf16(t[1]);
        u.z = rne_bf16(t[2]); u.w = rne_bf16(t[3]);
        *(ushort4*)(Xout + (pixbase + px) * OSTRIDE + co) = u;
      }
      if (COF32 > 0) {
#pragma unroll
        for (int r = 0; r < 4; ++r) {
          int c = co + r;
          if (c < COF32)
            outF[(((size_t)bi * COF32 + c) << 16) + (h << 8) + px] = t[r];
        }
      }
    }
  }
}

// ---------------------------------------------------------------------------
// Old direct-global conv kernel, kept for tiny conv6 (M=16, K=576).
// ---------------------------------------------------------------------------
template<int CI, int COP, int MF, int KS, bool LRELU, bool OBF, int COF32>
__global__ __launch_bounds__(256) void conv_kernel(const u16* __restrict__ Xin,
                                                   const u16* __restrict__ Wp,
                                                   const float* __restrict__ bias,
                                                   u16* __restrict__ Xout, int ostride,
                                                   float* __restrict__ outF) {
  const int lane = threadIdx.x & 63, wv = threadIdx.x >> 6;
  const int bi = blockIdx.x >> 9;
  const int h = (blockIdx.x >> 1) & 255;
  const int w0 = (blockIdx.x & 1) << 7;
  const int co0 = blockIdx.y * (MF * 16);
  const int l15 = lane & 15, klane = (lane >> 4) << 3;
  const int ncol0 = w0 + wv * 32 + l15;
  const int rowbase = (bi << 8) + h;

  const f32x4 zf = {0.f, 0.f, 0.f, 0.f};
  const short8 z8 = {0, 0, 0, 0, 0, 0, 0, 0};
  f32x4 acc[MF][2];
#pragma unroll
  for (int m = 0; m < MF; ++m) { acc[m][0] = zf; acc[m][1] = zf; }

#pragma unroll 1
  for (int chunk = 0; chunk < CI / 32; ++chunk) {
#pragma unroll
    for (int tap = 0; tap < KS * KS; ++tap) {
      const int dy = (KS == 3) ? tap / 3 - 1 : 0;
      const int dx = (KS == 3) ? tap % 3 - 1 : 0;
      const int hin = h + dy;
      if (KS == 3 && (unsigned)hin >= 256u) continue;
      short8 bf[2];
#pragma unroll
      for (int nf = 0; nf < 2; ++nf) {
        int win = ncol0 + nf * 16 + dx;
        short8 v = z8;
        if (KS == 1 || (unsigned)win < 256u)
          v = *(const short8*)(Xin + ((size_t)(((bi << 8) + hin) * 256 + win)) * CI
                               + chunk * 32 + klane);
        bf[nf] = v;
      }
#pragma unroll
      for (int m = 0; m < MF; ++m) {
        const short8 af = *(const short8*)(Wp + ((size_t)(tap * COP + co0 + m * 16 + l15)) * CI
                                           + chunk * 32 + klane);
        mfma16(af, bf[0], acc[m][0]);
        mfma16(af, bf[1], acc[m][1]);
      }
    }
  }
  asm volatile("s_nop 7\n\ts_nop 7");

  const int co_sub = (lane >> 4) << 2;
  const size_t pixrow = (size_t)rowbase << 8;
#pragma unroll
  for (int m = 0; m < MF; ++m) {
    const int co = co0 + m * 16 + co_sub;
#pragma unroll
    for (int nf = 0; nf < 2; ++nf) {
      const int w = ncol0 + nf * 16;
      f32x4 v = acc[m][nf];
      if constexpr (OBF) {
        float t[4];
#pragma unroll
        for (int r = 0; r < 4; ++r) {
          float x = v[r] + bias[co + r];
          if constexpr (LRELU) x = x > 0.f ? x : 0.1f * x;
          t[r] = x;
        }
        ushort4 u;
        u.x = rne_bf16(t[0]); u.y = rne_bf16(t[1]);
        u.z = rne_bf16(t[2]); u.w = rne_bf16(t[3]);
        *(ushort4*)(Xout + (pixrow + w) * (size_t)ostride + co) = u;
      }
      if constexpr (COF32 > 0) {
#pragma unroll
        for (int r = 0; r < 4; ++r) {
          int c = co + r;
          if (c < COF32) {
            float x = v[r] + bias[c];
            if constexpr (LRELU) x = x > 0.f ? x : 0.1f * x;
            outF[((((size_t)bi * COF32) + c) << 16) + (h << 8) + w] = x;
          }
        }
      }
    }
  }
}

// ---------------------------------------------------------------------------
extern "C" void kernel_launch(void* const* d_in, const int* in_sizes, int n_in,
                              void* d_out, int out_size, void* d_ws, size_t ws_size,
                              hipStream_t stream) {
  const float* feat0 = (const float*)d_in[0];
  const float* feat1 = (const float*)d_in[1];
  const float* lfeat = (const float*)d_in[2];
  const float* lflow = (const float*)d_in[3];
  const float* w1 = (const float*)d_in[4];  const float* b1 = (const float*)d_in[5];
  const float* w2 = (const float*)d_in[6];  const float* b2 = (const float*)d_in[7];
  const float* w3 = (const float*)d_in[8];  const float* b3 = (const float*)d_in[9];
  const float* w4 = (const float*)d_in[10]; const float* b4 = (const float*)d_in[11];
  const float* w5 = (const float*)d_in[12]; const float* b5 = (const float*)d_in[13];
  const float* w6 = (const float*)d_in[14]; const float* b6 = (const float*)d_in[15];

  u16* ws = (u16*)d_ws;
  // Region A (elem 0): X1 [131072][256] -> X3 [131072][128] -> X5 [131072][96]
  // Region B (elem 33554432): X2 [131072][160] -> X4 [131072][128] -> X6 [131072][64]
  u16* X1 = ws;
  u16* X2 = ws + 33554432;
  u16* X3 = ws;
  u16* X4 = ws + 33554432;
  u16* X5 = ws;
  u16* X6 = ws + 33554432;
  u16* w1p = ws + 54525952;      // [192][256]
  u16* w2p = w1p + 49152;        // [9][128][160]
  u16* w3p = w2p + 184320;       // [9][128][128] (co 112..127 zero)
  u16* w4p = w3p + 147456;       // [9][128][128] (co 96..127, ci 112..127 zero)
  u16* w5p = w4p + 147456;       // [9][64][96]
  u16* w6p = w5p + 55296;        // [9][16][64]  (co 4..15 zero)
  float* bp = (float*)(w6p + 9216);  // 576 f32: b1|b2|b3pad|b4|b5
  u16* zbuf = (u16*)(bp + 576);      // 128 zero bf16 (OOB gather stub)

  const float* bp1 = bp;
  const float* bp2 = bp + 160;
  const float* bp3 = bp + 288;
  const float* bp4 = bp + 416;
  const float* bp5 = bp + 512;

  float* flow = (float*)d_out;              // [2][4][256][256]
  float* xout = (float*)d_out + 524288;     // [2][64][256][256]

  prep1_kernel<<<192, 256, 0, stream>>>(w1, w1p);
  prep3_kernel<128, 160, 128, 160><<<720, 256, 0, stream>>>(w2, w2p);
  prep3_kernel<112, 128, 128, 128><<<576, 256, 0, stream>>>(w3, w3p);
  prep3_kernel< 96, 112, 128, 128><<<576, 256, 0, stream>>>(w4, w4p);
  prep3_kernel< 64,  96,  64,  96><<<216, 256, 0, stream>>>(w5, w5p);
  prep3_kernel<  4,  64,  16,  64><<< 36, 256, 0, stream>>>(w6, w6p);
  prep_bias_kernel<<<3, 256, 0, stream>>>(b1, b2, b3, b4, b5, bp, zbuf);

  corr_kernel<<<512, 256, 0, stream>>>(feat0, feat1, X1);
  concat_kernel<<<2048, 256, 0, stream>>>(feat0, feat1, lfeat, lflow, X1);

  // <CI, BM, ASTAGE, KS, OSTRIDE, LRELU, OBF, COF32>
  convg_kernel<256, 160, 192, 1, 160, true, true,  0><<<1024, 256, 0, stream>>>(X1, w1p, bp1, zbuf, X2, nullptr);
  convg_kernel<160, 128, 128, 3, 128, true, true,  0><<<1024, 256, 0, stream>>>(X2, w2p, bp2, zbuf, X3, nullptr);
  convg_kernel<128, 128, 128, 3, 128, true, true,  0><<<1024, 256, 0, stream>>>(X3, w3p, bp3, zbuf, X4, nullptr);
  convg_kernel<128,  96, 128, 3,  96, true, true,  0><<<1024, 256, 0, stream>>>(X4, w4p, bp4, zbuf, X5, nullptr);
  convg_kernel< 96,  64,  64, 3,  64, true, true, 64><<<1024, 256, 0, stream>>>(X5, w5p, bp5, zbuf, X6, xout);
  conv_kernel< 64,  16, 1, 3, false, false, 4><<<dim3(1024, 1), 256, 0, stream>>>(X6, w6p, b6, nullptr, 0, flow);
}

// Round 3
// 376.308 us; speedup vs baseline: 2.9829x; 1.3785x over previous
//
#include <hip/hip_runtime.h>
#include <cstdint>
#include <cstddef>

// ---------------------------------------------------------------------------
// Optical-flow estimator head, MI355X bf16 MFMA implementation. Round 3:
// corr rewritten as f16-dot2 LDS-window kernel (was 220us, 42% of total).
// Convs unchanged from round 2 (LDS-staged implicit GEMM, m97 structure).
//
// X layout: NHWC bf16, [pix = b*65536 + h*256 + w][C_stride]
// conv1 K-order permuted: X1 = [feats 0..163 | volume 164..244 | zero 245..255]
// ---------------------------------------------------------------------------

using short8 = __attribute__((ext_vector_type(8))) short;
using f32x4  = __attribute__((ext_vector_type(4))) float;
typedef unsigned short u16;

__device__ __forceinline__ u16 rne_bf16(float f) {
  unsigned u = __float_as_uint(f);
  u += 0x7FFFu + ((u >> 16) & 1u);   // round-to-nearest-even
  return (u16)(u >> 16);
}

__device__ __forceinline__ void mfma16(const short8& a, const short8& b, f32x4& c) {
  asm("v_mfma_f32_16x16x32_bf16 %0, %1, %2, %0" : "+v"(c) : "v"(a), "v"(b));
}

// packed f32x2 -> f16x2 (RTZ)
__device__ __forceinline__ unsigned pk_f16(float a, float b) {
  unsigned r;
  asm("v_cvt_pkrtz_f16_f32 %0, %1, %2" : "=v"(r) : "v"(a), "v"(b));
  return r;
}

// acc += dot(2xf16 a, 2xf16 b), f32 accumulate
__device__ __forceinline__ void dot2(float& acc, unsigned a, unsigned b) {
  asm("v_dot2_f32_f16 %0, %1, %2, %0" : "+v"(acc) : "v"(a), "v"(b));
}

// async global -> LDS, 16B per lane
__device__ __forceinline__ void gload16(const void* g, void* l) {
  __builtin_amdgcn_global_load_lds(
      (const __attribute__((address_space(1))) unsigned int*)g,
      (__attribute__((address_space(3))) unsigned int*)l, 16, 0, 0);
}

// ---------------------------------------------------------------------------
// Weight prep
// ---------------------------------------------------------------------------
__global__ __launch_bounds__(256) void prep1_kernel(const float* __restrict__ w1,
                                                    u16* __restrict__ w1p) {
  int idx = blockIdx.x * 256 + threadIdx.x;     // < 192*256
  int co = idx >> 8, cip = idx & 255;
  float v = 0.f;
  if (co < 160 && cip < 245) {
    int ci = (cip < 164) ? (cip + 81) : (cip - 164);
    v = w1[co * 245 + ci];
  }
  w1p[idx] = rne_bf16(v);
}

template<int CO, int CI, int COP, int CIP>
__global__ __launch_bounds__(256) void prep3_kernel(const float* __restrict__ w,
                                                    u16* __restrict__ wp) {
  int idx = blockIdx.x * 256 + threadIdx.x;     // < 9*COP*CIP
  int ci = idx % CIP; int rest = idx / CIP;
  int co = rest % COP; int tap = rest / COP;
  float v = 0.f;
  if (co < CO && ci < CI) v = w[(co * CI + ci) * 9 + tap];
  wp[idx] = rne_bf16(v);
}

__global__ __launch_bounds__(256) void prep_bias_kernel(const float* __restrict__ b1,
    const float* __restrict__ b2, const float* __restrict__ b3,
    const float* __restrict__ b4, const float* __restrict__ b5,
    float* __restrict__ bp, u16* __restrict__ zbuf) {
  int i = blockIdx.x * 256 + threadIdx.x;       // grid 3 blocks
  if (i < 128) zbuf[i] = 0;
  float v = 0.f;
  if (i < 160) v = b1[i];
  else if (i < 288) v = b2[i - 160];
  else if (i < 416) { int c = i - 288; v = (c < 112) ? b3[c] : 0.f; }
  else if (i < 512) v = b4[i - 416];
  else if (i < 576) v = b5[i - 512];
  else return;
  bp[i] = v;
}

// ---------------------------------------------------------------------------
// Correlation, round-3 design.
// Block = (b, 2 output rows, 64-col tile); 1024 blocks, XCD-swizzled.
// Window LDS: [6 cpp][10 r][72 c][4 ch] f16 (uint2 units) = 34.5 KB, 2 chunks
// of 24 ch. Wave 0/1: rows 0/1 with dy 0..3 (36 taps); wave 2/3: dy 4..8 (45).
// Per thread: 24 ch-pairs via v_dot2_f32_f16, cv in regs, packed bf16 stores.
// ---------------------------------------------------------------------------
template<int NDY>
__device__ __forceinline__ void corr_compute(const uint2* __restrict__ win_s,
                                             const unsigned* __restrict__ f0p,
                                             float* __restrict__ cv,
                                             int row, int col, int dy0) {
#pragma unroll
  for (int d = 0; d < NDY; ++d) {
    const int r = row + dy0 + d;
#pragma unroll
    for (int cpp = 0; cpp < 6; ++cpp) {
      const uint2* base = win_s + (cpp * 10 + r) * 72 + col;
#pragma unroll
      for (int dx = 0; dx < 9; ++dx) {
        const uint2 v = base[dx];
        dot2(cv[d * 9 + dx], v.x, f0p[2 * cpp]);
        dot2(cv[d * 9 + dx], v.y, f0p[2 * cpp + 1]);
      }
    }
  }
}

__global__ __launch_bounds__(256) void corr2_kernel(const float* __restrict__ f0,
                                                    const float* __restrict__ f1,
                                                    u16* __restrict__ X1) {
  __shared__ uint2 win_s[4320];          // [6][10][72] uint2 (4 f16 ch each)
  const int bid = blockIdx.x;
  const int swz = (bid & 7) * 128 + (bid >> 3);   // XCD-contiguous (1024 % 8 == 0)
  const int b = swz >> 9, rest = swz & 511;
  const int hp = rest >> 2, ct = rest & 3;
  const int h0 = hp << 1, w0 = ct << 6;
  const int tid = threadIdx.x, lane = tid & 63, wv = tid >> 6;
  const int half = wv >> 1, row = wv & 1, col = lane;

  float cv[45];
#pragma unroll
  for (int t = 0; t < 45; ++t) cv[t] = 0.f;

#pragma unroll 1
  for (int cc = 0; cc < 2; ++cc) {
    if (cc) __syncthreads();             // drain chunk-0 reads before overwrite
    // ---- f0 pairs for this chunk (12 regs) ----
    unsigned f0p[12];
    {
      const float* p0 = f0 + (((size_t)(b * 48 + cc * 24)) << 16)
                           + ((h0 + row) << 8) + (w0 + col);
#pragma unroll
      for (int j = 0; j < 12; ++j)
        f0p[j] = pk_f16(p0[(2 * j) << 16], p0[(2 * j + 1) << 16]);
    }
    // ---- stage f1 window (24 ch as 6 quads) ----
#pragma unroll 1
    for (int i = tid; i < 4320; i += 256) {
      const int c = i % 72;
      const int q = i / 72;
      const int r = q % 10;
      const int cpp = q / 10;
      const int hin = h0 + r - 4, win = w0 + c - 4;
      float v0 = 0.f, v1 = 0.f, v2 = 0.f, v3 = 0.f;
      if ((unsigned)hin < 256u && (unsigned)win < 256u) {
        const float* p = f1 + (((size_t)(b * 48 + cc * 24 + cpp * 4)) << 16)
                            + (hin << 8) + win;
        v0 = p[0]; v1 = p[1 << 16]; v2 = p[2 << 16]; v3 = p[3 << 16];
      }
      win_s[i] = make_uint2(pk_f16(v0, v1), pk_f16(v2, v3));
    }
    __syncthreads();
    if (half == 0) corr_compute<4>(win_s, f0p, cv, row, col, 0);
    else           corr_compute<5>(win_s, f0p, cv, row, col, 4);
  }

  // ---- scale, lrelu, bf16-pack, store ----
  const size_t pix = ((size_t)b << 16) + ((size_t)(h0 + row) << 8) + (w0 + col);
  u16* dst = X1 + pix * 256;
  const float sc = 1.0f / 48.0f;
  if (half == 0) {
    // taps 0..35 -> ch 164..199 (9 uint2)
#pragma unroll
    for (int qq = 0; qq < 9; ++qq) {
      u16 e[4];
#pragma unroll
      for (int j = 0; j < 4; ++j) {
        float v = cv[qq * 4 + j] * sc;
        v = v > 0.f ? v : 0.1f * v;
        e[j] = rne_bf16(v);
      }
      uint2 u;
      u.x = (unsigned)e[0] | ((unsigned)e[1] << 16);
      u.y = (unsigned)e[2] | ((unsigned)e[3] << 16);
      *(uint2*)(dst + 164 + qq * 4) = u;
    }
  } else {
    // taps 36..80 -> ch 200..244, zeros through ch 255 (14 uint2)
#pragma unroll
    for (int qq = 0; qq < 14; ++qq) {
      u16 e[4];
#pragma unroll
      for (int j = 0; j < 4; ++j) {
        int t = qq * 4 + j;
        float v = 0.f;
        if (t < 45) {
          v = cv[t] * sc;
          v = v > 0.f ? v : 0.1f * v;
        }
        e[j] = rne_bf16(v);
      }
      uint2 u;
      u.x = (unsigned)e[0] | ((unsigned)e[1] << 16);
      u.y = (unsigned)e[2] | ((unsigned)e[3] << 16);
      *(uint2*)(dst + 200 + qq * 4) = u;
    }
  }
}

// ---------------------------------------------------------------------------
// Concat: NCHW f32 sources -> X1 NHWC bf16 channels 0..163
// ---------------------------------------------------------------------------
__global__ __launch_bounds__(256) void concat_kernel(const float* __restrict__ f0,
                                                     const float* __restrict__ f1,
                                                     const float* __restrict__ lf,
                                                     const float* __restrict__ lfl,
                                                     u16* __restrict__ X1) {
  __shared__ float s[16][68];
  const int t = threadIdx.x;
  const size_t px0 = (size_t)blockIdx.x * 64;
  const int b = blockIdx.x >> 10;
  const int hw0 = (blockIdx.x & 1023) * 64;

#pragma unroll 1
  for (int cc = 0; cc < 11; ++cc) {
    __syncthreads();
    {
      int px = t & 63, cg = t >> 6;
#pragma unroll
      for (int r = 0; r < 4; ++r) {
        int cl = cg * 4 + r;
        int c = cc * 16 + cl;
        int hw = hw0 + px;
        float v = 0.f;
        if (c < 48)       v = f0[(((size_t)(b * 48 + c)) << 16) + hw];
        else if (c < 96)  v = f1[(((size_t)(b * 48 + (c - 48))) << 16) + hw];
        else if (c < 160) v = lf[(((size_t)(b * 64 + (c - 96))) << 16) + hw];
        else if (c < 164) v = lfl[(((size_t)(b * 4 + (c - 160))) << 16) + hw];
        s[cl][px] = v;
      }
    }
    __syncthreads();
    {
      int px = t >> 2, g = t & 3;
      int cbase = cc * 16 + g * 4;
      if (cbase < 164) {
        ushort4 u;
        u.x = rne_bf16(s[g * 4 + 0][px]);
        u.y = rne_bf16(s[g * 4 + 1][px]);
        u.z = rne_bf16(s[g * 4 + 2][px]);
        u.w = rne_bf16(s[g * 4 + 3][px]);
        *(ushort4*)(X1 + (px0 + px) * 256 + cbase) = u;
      }
    }
  }
}

// ---------------------------------------------------------------------------
// LDS-staged implicit-GEMM conv (m97 structure), unchanged from round 2.
// ---------------------------------------------------------------------------
template<int CI, int BM, int ASTAGE, int KS, int OSTRIDE, bool LRELU, bool OBF, int COF32>
__global__ __launch_bounds__(256) void convg_kernel(const u16* __restrict__ Xin,
    const u16* __restrict__ Wp, const float* __restrict__ bias,
    const u16* __restrict__ zbuf, u16* __restrict__ Xout,
    float* __restrict__ outF) {
  constexpr int MF  = BM / 32;
  constexpr int AR  = (ASTAGE * 64) / 4096;
  constexpr int NCH = CI / 32;
  __shared__ u16 lA[ASTAGE * 32];
  __shared__ u16 lB[128 * 32];
  const int tid  = threadIdx.x;
  const int lane = tid & 63, wv = tid >> 6;
  const int wm = wv >> 1, wn = wv & 1;
  const int bi = blockIdx.x >> 9;
  const int h  = (blockIdx.x >> 1) & 255;
  const int w0 = (blockIdx.x & 1) << 7;
  const int l15 = lane & 15, k8 = (lane >> 4) << 3;

  f32x4 acc[MF][4];
  const f32x4 zf = {0.f, 0.f, 0.f, 0.f};
#pragma unroll
  for (int m = 0; m < MF; ++m)
#pragma unroll
    for (int n = 0; n < 4; ++n) acc[m][n] = zf;

#pragma unroll 1
  for (int tap = 0; tap < KS * KS; ++tap) {
    const int dy = (KS == 3) ? tap / 3 - 1 : 0;
    const int dx = (KS == 3) ? tap % 3 - 1 : 0;
    const int hin = h + dy;
    if (KS == 3 && (unsigned)hin >= 256u) continue;
    const u16* Wtap = Wp + (size_t)tap * ASTAGE * CI;
    const u16* Brow = Xin + (((size_t)((bi << 8) + hin)) << 8) * CI;

    const u16* asrc[AR];
#pragma unroll
    for (int r = 0; r < AR; ++r) {
      int idx = r * 256 + tid;
      asrc[r] = Wtap + (size_t)(idx >> 2) * CI + (idx & 3) * 8;
    }
    const u16* bsrc[2];
#pragma unroll
    for (int r = 0; r < 2; ++r) {
      int idx = r * 256 + tid;
      int px = idx >> 2, c16 = idx & 3;
      int win = w0 + dx + px;
      bsrc[r] = (KS == 1 || (unsigned)win < 256u)
                    ? (Brow + (size_t)win * CI + c16 * 8)
                    : (zbuf + c16 * 8);
    }

#pragma unroll 1
    for (int chunk = 0; chunk < NCH; ++chunk) {
      __syncthreads();
#pragma unroll
      for (int r = 0; r < AR; ++r)
        gload16(asrc[r] + chunk * 32, &lA[r * 2048 + wv * 512]);
#pragma unroll
      for (int r = 0; r < 2; ++r)
        gload16(bsrc[r] + chunk * 32, &lB[r * 2048 + wv * 512]);
      __syncthreads();

      short8 af[MF], bf[4];
#pragma unroll
      for (int m = 0; m < MF; ++m)
        af[m] = *(const short8*)&lA[(wm * (BM / 2) + m * 16 + l15) * 32 + k8];
#pragma unroll
      for (int n = 0; n < 4; ++n)
        bf[n] = *(const short8*)&lB[(wn * 64 + n * 16 + l15) * 32 + k8];
#pragma unroll
      for (int m = 0; m < MF; ++m)
#pragma unroll
        for (int n = 0; n < 4; ++n) mfma16(af[m], bf[n], acc[m][n]);
    }
  }
  asm volatile("s_nop 7\n\ts_nop 7");

  const int co_sub = (lane >> 4) << 2;
  const size_t pixbase = ((size_t)((bi << 8) + h)) << 8;
#pragma unroll
  for (int m = 0; m < MF; ++m) {
    const int co = wm * (BM / 2) + m * 16 + co_sub;
#pragma unroll
    for (int n = 0; n < 4; ++n) {
      const int px = w0 + wn * 64 + n * 16 + l15;
      f32x4 v = acc[m][n];
      float t[4];
#pragma unroll
      for (int r = 0; r < 4; ++r) {
        float x = v[r] + bias[co + r];
        if (LRELU) x = x > 0.f ? x : 0.1f * x;
        t[r] = x;
      }
      if (OBF) {
        ushort4 u;
        u.x = rne_bf16(t[0]); u.y = rne_bf16(t[1]);
        u.z = rne_bf16(t[2]); u.w = rne_bf16(t[3]);
        *(ushort4*)(Xout + (pixbase + px) * OSTRIDE + co) = u;
      }
      if (COF32 > 0) {
#pragma unroll
        for (int r = 0; r < 4; ++r) {
          int c = co + r;
          if (c < COF32)
            outF[(((size_t)bi * COF32 + c) << 16) + (h << 8) + px] = t[r];
        }
      }
    }
  }
}

// ---------------------------------------------------------------------------
// Old direct-global conv kernel, kept for tiny conv6 (M=16, K=576).
// ---------------------------------------------------------------------------
template<int CI, int COP, int MF, int KS, bool LRELU, bool OBF, int COF32>
__global__ __launch_bounds__(256) void conv_kernel(const u16* __restrict__ Xin,
                                                   const u16* __restrict__ Wp,
                                                   const float* __restrict__ bias,
                                                   u16* __restrict__ Xout, int ostride,
                                                   float* __restrict__ outF) {
  const int lane = threadIdx.x & 63, wv = threadIdx.x >> 6;
  const int bi = blockIdx.x >> 9;
  const int h = (blockIdx.x >> 1) & 255;
  const int w0 = (blockIdx.x & 1) << 7;
  const int co0 = blockIdx.y * (MF * 16);
  const int l15 = lane & 15, klane = (lane >> 4) << 3;
  const int ncol0 = w0 + wv * 32 + l15;
  const int rowbase = (bi << 8) + h;

  const f32x4 zf = {0.f, 0.f, 0.f, 0.f};
  const short8 z8 = {0, 0, 0, 0, 0, 0, 0, 0};
  f32x4 acc[MF][2];
#pragma unroll
  for (int m = 0; m < MF; ++m) { acc[m][0] = zf; acc[m][1] = zf; }

#pragma unroll 1
  for (int chunk = 0; chunk < CI / 32; ++chunk) {
#pragma unroll
    for (int tap = 0; tap < KS * KS; ++tap) {
      const int dy = (KS == 3) ? tap / 3 - 1 : 0;
      const int dx = (KS == 3) ? tap % 3 - 1 : 0;
      const int hin = h + dy;
      if (KS == 3 && (unsigned)hin >= 256u) continue;
      short8 bf[2];
#pragma unroll
      for (int nf = 0; nf < 2; ++nf) {
        int win = ncol0 + nf * 16 + dx;
        short8 v = z8;
        if (KS == 1 || (unsigned)win < 256u)
          v = *(const short8*)(Xin + ((size_t)(((bi << 8) + hin) * 256 + win)) * CI
                               + chunk * 32 + klane);
        bf[nf] = v;
      }
#pragma unroll
      for (int m = 0; m < MF; ++m) {
        const short8 af = *(const short8*)(Wp + ((size_t)(tap * COP + co0 + m * 16 + l15)) * CI
                                           + chunk * 32 + klane);
        mfma16(af, bf[0], acc[m][0]);
        mfma16(af, bf[1], acc[m][1]);
      }
    }
  }
  asm volatile("s_nop 7\n\ts_nop 7");

  const int co_sub = (lane >> 4) << 2;
  const size_t pixrow = (size_t)rowbase << 8;
#pragma unroll
  for (int m = 0; m < MF; ++m) {
    const int co = co0 + m * 16 + co_sub;
#pragma unroll
    for (int nf = 0; nf < 2; ++nf) {
      const int w = ncol0 + nf * 16;
      f32x4 v = acc[m][nf];
      if constexpr (OBF) {
        float t[4];
#pragma unroll
        for (int r = 0; r < 4; ++r) {
          float x = v[r] + bias[co + r];
          if constexpr (LRELU) x = x > 0.f ? x : 0.1f * x;
          t[r] = x;
        }
        ushort4 u;
        u.x = rne_bf16(t[0]); u.y = rne_bf16(t[1]);
        u.z = rne_bf16(t[2]); u.w = rne_bf16(t[3]);
        *(ushort4*)(Xout + (pixrow + w) * (size_t)ostride + co) = u;
      }
      if constexpr (COF32 > 0) {
#pragma unroll
        for (int r = 0; r < 4; ++r) {
          int c = co + r;
          if (c < COF32) {
            float x = v[r] + bias[c];
            if constexpr (LRELU) x = x > 0.f ? x : 0.1f * x;
            outF[((((size_t)bi * COF32) + c) << 16) + (h << 8) + w] = x;
          }
        }
      }
    }
  }
}

// ---------------------------------------------------------------------------
extern "C" void kernel_launch(void* const* d_in, const int* in_sizes, int n_in,
                              void* d_out, int out_size, void* d_ws, size_t ws_size,
                              hipStream_t stream) {
  const float* feat0 = (const float*)d_in[0];
  const float* feat1 = (const float*)d_in[1];
  const float* lfeat = (const float*)d_in[2];
  const float* lflow = (const float*)d_in[3];
  const float* w1 = (const float*)d_in[4];  const float* b1 = (const float*)d_in[5];
  const float* w2 = (const float*)d_in[6];  const float* b2 = (const float*)d_in[7];
  const float* w3 = (const float*)d_in[8];  const float* b3 = (const float*)d_in[9];
  const float* w4 = (const float*)d_in[10]; const float* b4 = (const float*)d_in[11];
  const float* w5 = (const float*)d_in[12]; const float* b5 = (const float*)d_in[13];
  const float* w6 = (const float*)d_in[14]; const float* b6 = (const float*)d_in[15];

  u16* ws = (u16*)d_ws;
  u16* X1 = ws;
  u16* X2 = ws + 33554432;
  u16* X3 = ws;
  u16* X4 = ws + 33554432;
  u16* X5 = ws;
  u16* X6 = ws + 33554432;
  u16* w1p = ws + 54525952;      // [192][256]
  u16* w2p = w1p + 49152;        // [9][128][160]
  u16* w3p = w2p + 184320;       // [9][128][128]
  u16* w4p = w3p + 147456;       // [9][128][128]
  u16* w5p = w4p + 147456;       // [9][64][96]
  u16* w6p = w5p + 55296;        // [9][16][64]
  float* bp = (float*)(w6p + 9216);  // 576 f32
  u16* zbuf = (u16*)(bp + 576);      // 128 zero bf16

  const float* bp1 = bp;
  const float* bp2 = bp + 160;
  const float* bp3 = bp + 288;
  const float* bp4 = bp + 416;
  const float* bp5 = bp + 512;

  float* flow = (float*)d_out;              // [2][4][256][256]
  float* xout = (float*)d_out + 524288;     // [2][64][256][256]

  prep1_kernel<<<192, 256, 0, stream>>>(w1, w1p);
  prep3_kernel<128, 160, 128, 160><<<720, 256, 0, stream>>>(w2, w2p);
  prep3_kernel<112, 128, 128, 128><<<576, 256, 0, stream>>>(w3, w3p);
  prep3_kernel< 96, 112, 128, 128><<<576, 256, 0, stream>>>(w4, w4p);
  prep3_kernel< 64,  96,  64,  96><<<216, 256, 0, stream>>>(w5, w5p);
  prep3_kernel<  4,  64,  16,  64><<< 36, 256, 0, stream>>>(w6, w6p);
  prep_bias_kernel<<<3, 256, 0, stream>>>(b1, b2, b3, b4, b5, bp, zbuf);

  corr2_kernel<<<1024, 256, 0, stream>>>(feat0, feat1, X1);
  concat_kernel<<<2048, 256, 0, stream>>>(feat0, feat1, lfeat, lflow, X1);

  // <CI, BM, ASTAGE, KS, OSTRIDE, LRELU, OBF, COF32>
  convg_kernel<256, 160, 192, 1, 160, true, true,  0><<<1024, 256, 0, stream>>>(X1, w1p, bp1, zbuf, X2, nullptr);
  convg_kernel<160, 128, 128, 3, 128, true, true,  0><<<1024, 256, 0, stream>>>(X2, w2p, bp2, zbuf, X3, nullptr);
  convg_kernel<128, 128, 128, 3, 128, true, true,  0><<<1024, 256, 0, stream>>>(X3, w3p, bp3, zbuf, X4, nullptr);
  convg_kernel<128,  96, 128, 3,  96, true, true,  0><<<1024, 256, 0, stream>>>(X4, w4p, bp4, zbuf, X5, nullptr);
  convg_kernel< 96,  64,  64, 3,  64, true, true, 64><<<1024, 256, 0, stream>>>(X5, w5p, bp5, zbuf, X6, xout);
  conv_kernel< 64,  16, 1, 3, false, false, 4><<<dim3(1024, 1), 256, 0, stream>>>(X6, w6p, b6, nullptr, 0, flow);
}

// Round 4
// 330.214 us; speedup vs baseline: 3.3993x; 1.1396x over previous
//
#include <hip/hip_runtime.h>
#include <cstdint>
#include <cstddef>

// ---------------------------------------------------------------------------
// Optical-flow estimator head, MI355X bf16 MFMA implementation. Round 4:
// convs restructured to merged-tap phases (one dy row + 3 dx taps per
// barrier-pair), XOR bank-swizzled LDS (pre-swizzled gather sources),
// XCD-bijective grid swizzle. corr/concat unchanged from round 3.
//
// X layout: NHWC bf16, [pix = b*65536 + h*256 + w][C_stride]
// conv1 K-order permuted: X1 = [feats 0..163 | volume 164..244 | zero 245..255]
// 3x3 weights packed [dy][APLN rows = dx*BM+co, padded][CI].
// ---------------------------------------------------------------------------

using short8 = __attribute__((ext_vector_type(8))) short;
using f32x4  = __attribute__((ext_vector_type(4))) float;
typedef unsigned short u16;

__device__ __forceinline__ u16 rne_bf16(float f) {
  unsigned u = __float_as_uint(f);
  u += 0x7FFFu + ((u >> 16) & 1u);   // round-to-nearest-even
  return (u16)(u >> 16);
}

__device__ __forceinline__ void mfma16(const short8& a, const short8& b, f32x4& c) {
  asm("v_mfma_f32_16x16x32_bf16 %0, %1, %2, %0" : "+v"(c) : "v"(a), "v"(b));
}

__device__ __forceinline__ unsigned pk_f16(float a, float b) {
  unsigned r;
  asm("v_cvt_pkrtz_f16_f32 %0, %1, %2" : "=v"(r) : "v"(a), "v"(b));
  return r;
}

__device__ __forceinline__ void dot2(float& acc, unsigned a, unsigned b) {
  asm("v_dot2_f32_f16 %0, %1, %2, %0" : "+v"(acc) : "v"(a), "v"(b));
}

// async global -> LDS, 16B per lane. LDS dest wave-uniform base + lane*16;
// global source is per-lane (gather allowed).
__device__ __forceinline__ void gload16(const void* g, void* l) {
  __builtin_amdgcn_global_load_lds(
      (const __attribute__((address_space(1))) unsigned int*)g,
      (__attribute__((address_space(3))) unsigned int*)l, 16, 0, 0);
}

// ---------------------------------------------------------------------------
// Weight prep
// ---------------------------------------------------------------------------
// w1 [160][245] f32 -> w1p [192][256] bf16 (rows 160..191 zero) with K-perm.
__global__ __launch_bounds__(256) void prep1_kernel(const float* __restrict__ w1,
                                                    u16* __restrict__ w1p) {
  int idx = blockIdx.x * 256 + threadIdx.x;     // < 192*256
  int co = idx >> 8, cip = idx & 255;
  float v = 0.f;
  if (co < 160 && cip < 245) {
    int ci = (cip < 164) ? (cip + 81) : (cip - 164);
    v = w1[co * 245 + ci];
  }
  w1p[idx] = rne_bf16(v);
}

// 3x3 weights -> [dy][APLN][CIP] bf16, row = dx*BM + co (padded rows/ci zero)
template<int CO, int CIr, int BM, int APLN, int CIP>
__global__ __launch_bounds__(256) void prep3s_kernel(const float* __restrict__ w,
                                                     u16* __restrict__ wp) {
  int idx = blockIdx.x * 256 + threadIdx.x;     // < 3*APLN*CIP
  int ci = idx % CIP; int rest = idx / CIP;
  int row = rest % APLN; int dyp = rest / APLN;
  int dx = row / BM, co = row % BM;
  float v = 0.f;
  if (dx < 3 && co < CO && ci < CIr)
    v = w[(co * CIr + ci) * 9 + dyp * 3 + dx];
  wp[idx] = rne_bf16(v);
}

// old flat layout for conv6: [tap][COP][CIP]
template<int CO, int CI, int COP, int CIP>
__global__ __launch_bounds__(256) void prep3_kernel(const float* __restrict__ w,
                                                    u16* __restrict__ wp) {
  int idx = blockIdx.x * 256 + threadIdx.x;     // < 9*COP*CIP
  int ci = idx % CIP; int rest = idx / CIP;
  int co = rest % COP; int tap = rest / COP;
  float v = 0.f;
  if (co < CO && ci < CI) v = w[(co * CI + ci) * 9 + tap];
  wp[idx] = rne_bf16(v);
}

__global__ __launch_bounds__(256) void prep_bias_kernel(const float* __restrict__ b1,
    const float* __restrict__ b2, const float* __restrict__ b3,
    const float* __restrict__ b4, const float* __restrict__ b5,
    float* __restrict__ bp, u16* __restrict__ zbuf) {
  int i = blockIdx.x * 256 + threadIdx.x;       // grid 3 blocks
  if (i < 128) zbuf[i] = 0;
  float v = 0.f;
  if (i < 160) v = b1[i];
  else if (i < 288) v = b2[i - 160];
  else if (i < 416) { int c = i - 288; v = (c < 112) ? b3[c] : 0.f; }
  else if (i < 512) v = b4[i - 416];
  else if (i < 576) v = b5[i - 512];
  else return;
  bp[i] = v;
}

// ---------------------------------------------------------------------------
// Correlation (round-3 design, unchanged).
// ---------------------------------------------------------------------------
template<int NDY>
__device__ __forceinline__ void corr_compute(const uint2* __restrict__ win_s,
                                             const unsigned* __restrict__ f0p,
                                             float* __restrict__ cv,
                                             int row, int col, int dy0) {
#pragma unroll
  for (int d = 0; d < NDY; ++d) {
    const int r = row + dy0 + d;
#pragma unroll
    for (int cpp = 0; cpp < 6; ++cpp) {
      const uint2* base = win_s + (cpp * 10 + r) * 72 + col;
#pragma unroll
      for (int dx = 0; dx < 9; ++dx) {
        const uint2 v = base[dx];
        dot2(cv[d * 9 + dx], v.x, f0p[2 * cpp]);
        dot2(cv[d * 9 + dx], v.y, f0p[2 * cpp + 1]);
      }
    }
  }
}

__global__ __launch_bounds__(256) void corr2_kernel(const float* __restrict__ f0,
                                                    const float* __restrict__ f1,
                                                    u16* __restrict__ X1) {
  __shared__ uint2 win_s[4320];          // [6][10][72]
  const int bid = blockIdx.x;
  const int swz = (bid & 7) * 128 + (bid >> 3);
  const int b = swz >> 9, rest = swz & 511;
  const int hp = rest >> 2, ct = rest & 3;
  const int h0 = hp << 1, w0 = ct << 6;
  const int tid = threadIdx.x, lane = tid & 63, wv = tid >> 6;
  const int half = wv >> 1, row = wv & 1, col = lane;

  float cv[45];
#pragma unroll
  for (int t = 0; t < 45; ++t) cv[t] = 0.f;

#pragma unroll 1
  for (int cc = 0; cc < 2; ++cc) {
    if (cc) __syncthreads();
    unsigned f0p[12];
    {
      const float* p0 = f0 + (((size_t)(b * 48 + cc * 24)) << 16)
                           + ((h0 + row) << 8) + (w0 + col);
#pragma unroll
      for (int j = 0; j < 12; ++j)
        f0p[j] = pk_f16(p0[(2 * j) << 16], p0[(2 * j + 1) << 16]);
    }
#pragma unroll 1
    for (int i = tid; i < 4320; i += 256) {
      const int c = i % 72;
      const int q = i / 72;
      const int r = q % 10;
      const int cpp = q / 10;
      const int hin = h0 + r - 4, win = w0 + c - 4;
      float v0 = 0.f, v1 = 0.f, v2 = 0.f, v3 = 0.f;
      if ((unsigned)hin < 256u && (unsigned)win < 256u) {
        const float* p = f1 + (((size_t)(b * 48 + cc * 24 + cpp * 4)) << 16)
                            + (hin << 8) + win;
        v0 = p[0]; v1 = p[1 << 16]; v2 = p[2 << 16]; v3 = p[3 << 16];
      }
      win_s[i] = make_uint2(pk_f16(v0, v1), pk_f16(v2, v3));
    }
    __syncthreads();
    if (half == 0) corr_compute<4>(win_s, f0p, cv, row, col, 0);
    else           corr_compute<5>(win_s, f0p, cv, row, col, 4);
  }

  const size_t pix = ((size_t)b << 16) + ((size_t)(h0 + row) << 8) + (w0 + col);
  u16* dst = X1 + pix * 256;
  const float sc = 1.0f / 48.0f;
  if (half == 0) {
#pragma unroll
    for (int qq = 0; qq < 9; ++qq) {
      u16 e[4];
#pragma unroll
      for (int j = 0; j < 4; ++j) {
        float v = cv[qq * 4 + j] * sc;
        v = v > 0.f ? v : 0.1f * v;
        e[j] = rne_bf16(v);
      }
      uint2 u;
      u.x = (unsigned)e[0] | ((unsigned)e[1] << 16);
      u.y = (unsigned)e[2] | ((unsigned)e[3] << 16);
      *(uint2*)(dst + 164 + qq * 4) = u;
    }
  } else {
#pragma unroll
    for (int qq = 0; qq < 14; ++qq) {
      u16 e[4];
#pragma unroll
      for (int j = 0; j < 4; ++j) {
        int t = qq * 4 + j;
        float v = 0.f;
        if (t < 45) {
          v = cv[t] * sc;
          v = v > 0.f ? v : 0.1f * v;
        }
        e[j] = rne_bf16(v);
      }
      uint2 u;
      u.x = (unsigned)e[0] | ((unsigned)e[1] << 16);
      u.y = (unsigned)e[2] | ((unsigned)e[3] << 16);
      *(uint2*)(dst + 200 + qq * 4) = u;
    }
  }
}

// ---------------------------------------------------------------------------
// Concat (unchanged).
// ---------------------------------------------------------------------------
__global__ __launch_bounds__(256) void concat_kernel(const float* __restrict__ f0,
                                                     const float* __restrict__ f1,
                                                     const float* __restrict__ lf,
                                                     const float* __restrict__ lfl,
                                                     u16* __restrict__ X1) {
  __shared__ float s[16][68];
  const int t = threadIdx.x;
  const size_t px0 = (size_t)blockIdx.x * 64;
  const int b = blockIdx.x >> 10;
  const int hw0 = (blockIdx.x & 1023) * 64;

#pragma unroll 1
  for (int cc = 0; cc < 11; ++cc) {
    __syncthreads();
    {
      int px = t & 63, cg = t >> 6;
#pragma unroll
      for (int r = 0; r < 4; ++r) {
        int cl = cg * 4 + r;
        int c = cc * 16 + cl;
        int hw = hw0 + px;
        float v = 0.f;
        if (c < 48)       v = f0[(((size_t)(b * 48 + c)) << 16) + hw];
        else if (c < 96)  v = f1[(((size_t)(b * 48 + (c - 48))) << 16) + hw];
        else if (c < 160) v = lf[(((size_t)(b * 64 + (c - 96))) << 16) + hw];
        else if (c < 164) v = lfl[(((size_t)(b * 4 + (c - 160))) << 16) + hw];
        s[cl][px] = v;
      }
    }
    __syncthreads();
    {
      int px = t >> 2, g = t & 3;
      int cbase = cc * 16 + g * 4;
      if (cbase < 164) {
        ushort4 u;
        u.x = rne_bf16(s[g * 4 + 0][px]);
        u.y = rne_bf16(s[g * 4 + 1][px]);
        u.z = rne_bf16(s[g * 4 + 2][px]);
        u.w = rne_bf16(s[g * 4 + 3][px]);
        *(ushort4*)(X1 + (px0 + px) * 256 + cbase) = u;
      }
    }
  }
}

// ---------------------------------------------------------------------------
// Merged-tap LDS-staged implicit-GEMM conv.
// Phase = (dy, ci-chunk): stage one B input row (w0-2..w0+129 halo, XOR-
// swizzled via pre-swizzled gather source) + A rows for all 3 dx taps,
// then 3 dx * MF*4 MFMAs per wave. Single-buffer, 2 barriers/phase.
// LDS slot byte = row*64 + (seg ^ ((row>>1)&3))*16  (seg = 16B quarter).
// ---------------------------------------------------------------------------
template<int CI, int BM, int APLN, int KS, int OSTRIDE, bool LRELU, bool OBF, int COF32>
__global__ __launch_bounds__(256) void convs_kernel(const u16* __restrict__ Xin,
    const u16* __restrict__ Wp, const float* __restrict__ bias,
    const u16* __restrict__ zbuf, u16* __restrict__ Xout,
    float* __restrict__ outF) {
  constexpr int NCH = CI / 32;
  constexpr int NDX = (KS == 3) ? 3 : 1;
  constexpr int AROUNDS = APLN / 64;          // 4KB staging rounds for A
  constexpr int BROUNDS = (KS == 3) ? 3 : 2;  // 192 / 128 px-slots
  constexpr int MF = BM / 32;                 // m-frags per wave
  constexpr int AELEMS = AROUNDS * 2048;      // u16 elems in A region
  constexpr int BPXMAX = (KS == 3) ? 132 : 128;
  __shared__ u16 lds[(AROUNDS + BROUNDS) * 2048];

  const int tid = threadIdx.x;
  const int lane = tid & 63, wv = tid >> 6;
  const int wm = wv >> 1, wn = wv & 1;
  const int bid = blockIdx.x;
  const int swz = (bid & 7) * 128 + (bid >> 3);   // XCD-contiguous, bijective
  const int bi = swz >> 9;
  const int h = (swz >> 1) & 255;
  const int w0 = (swz & 1) << 7;
  const int l15 = lane & 15, segr = lane >> 4;

  // per-thread staging source offsets (elems), swizzled
  size_t aofs[AROUNDS];
#pragma unroll
  for (int r = 0; r < AROUNDS; ++r) {
    int slot = r * 256 + tid;
    int row = slot >> 2, sp = slot & 3;
    int seg = sp ^ ((row >> 1) & 3);
    aofs[r] = (size_t)row * CI + seg * 8;
  }
  size_t bofs[BROUNDS];
  bool bcolv[BROUNDS];
#pragma unroll
  for (int r = 0; r < BROUNDS; ++r) {
    int slot = r * 256 + tid;
    int pxl = slot >> 2, sp = slot & 3;
    int seg = sp ^ ((pxl >> 1) & 3);
    int px = (KS == 3) ? (w0 + pxl - 2) : (w0 + pxl);
    bcolv[r] = ((unsigned)px < 256u) && (pxl < BPXMAX);
    bofs[r] = (size_t)px * CI + seg * 8;
  }

  f32x4 acc[MF][4];
  const f32x4 zf = {0.f, 0.f, 0.f, 0.f};
#pragma unroll
  for (int m = 0; m < MF; ++m)
#pragma unroll
    for (int n = 0; n < 4; ++n) acc[m][n] = zf;

  int dy = 0, c = 0;
#pragma unroll 1
  for (int ph = 0; ph < NDX * NCH; ++ph) {
    __syncthreads();                 // protect LDS from prev phase readers
    // ---- stage A (all dx taps, this dy, this chunk) ----
    const u16* Wph = Wp + ((size_t)dy * APLN) * CI + c * 32;
#pragma unroll
    for (int r = 0; r < AROUNDS; ++r)
      gload16(Wph + aofs[r], &lds[r * 2048 + wv * 512]);
    // ---- stage B (input row hin, halo, zbuf for OOB) ----
    const int hin = (KS == 3) ? (h + dy - 1) : h;
    const bool rv = (unsigned)hin < 256u;
    const u16* Brow = Xin + ((size_t)((bi << 8) + (rv ? hin : 0)) << 8) * CI + c * 32;
#pragma unroll
    for (int r = 0; r < BROUNDS; ++r) {
      const u16* src = (rv && bcolv[r]) ? (Brow + bofs[r]) : zbuf;
      gload16(src, &lds[AELEMS + r * 2048 + wv * 512]);
    }
    __syncthreads();                 // staging complete (vmcnt(0) by compiler)

    // ---- compute: NDX taps x MF x 4 MFMAs ----
#pragma unroll
    for (int dx = 0; dx < NDX; ++dx) {
      short8 bfr[4];
#pragma unroll
      for (int n = 0; n < 4; ++n) {
        int p = wn * 64 + n * 16 + l15;
        int pxl = (KS == 3) ? (p + dx + 1) : p;
        int ba = (AELEMS * 2) + pxl * 64 + ((segr ^ ((pxl >> 1) & 3)) << 4);
        bfr[n] = *(const short8*)((const char*)lds + ba);
      }
      short8 afr[MF];
#pragma unroll
      for (int m = 0; m < MF; ++m) {
        int row = dx * BM + wm * (BM / 2) + m * 16 + l15;
        int aa = row * 64 + ((segr ^ ((row >> 1) & 3)) << 4);
        afr[m] = *(const short8*)((const char*)lds + aa);
      }
#pragma unroll
      for (int m = 0; m < MF; ++m)
#pragma unroll
        for (int n = 0; n < 4; ++n) mfma16(afr[m], bfr[n], acc[m][n]);
    }
    if (++c == NCH) { c = 0; ++dy; }
  }
  asm volatile("s_nop 7\n\ts_nop 7");   // MFMA -> VALU hazard insurance

  // ---- epilogue ----
  const int co_sub = (lane >> 4) << 2;
  const size_t pixbase = ((size_t)((bi << 8) + h)) << 8;
#pragma unroll
  for (int m = 0; m < MF; ++m) {
    const int co = wm * (BM / 2) + m * 16 + co_sub;
#pragma unroll
    for (int n = 0; n < 4; ++n) {
      const int px = w0 + wn * 64 + n * 16 + l15;
      f32x4 v = acc[m][n];
      float t[4];
#pragma unroll
      for (int r = 0; r < 4; ++r) {
        float x = v[r] + bias[co + r];
        if (LRELU) x = x > 0.f ? x : 0.1f * x;
        t[r] = x;
      }
      if (OBF) {
        ushort4 u;
        u.x = rne_bf16(t[0]); u.y = rne_bf16(t[1]);
        u.z = rne_bf16(t[2]); u.w = rne_bf16(t[3]);
        *(ushort4*)(Xout + (pixbase + px) * OSTRIDE + co) = u;
      }
      if (COF32 > 0) {
#pragma unroll
        for (int r = 0; r < 4; ++r) {
          int cch = co + r;
          if (cch < COF32)
            outF[(((size_t)bi * COF32 + cch) << 16) + (h << 8) + px] = t[r];
        }
      }
    }
  }
}

// ---------------------------------------------------------------------------
// Old direct-global conv kernel for tiny conv6 (M=16, K=576).
// ---------------------------------------------------------------------------
template<int CI, int COP, int MF, int KS, bool LRELU, bool OBF, int COF32>
__global__ __launch_bounds__(256) void conv_kernel(const u16* __restrict__ Xin,
                                                   const u16* __restrict__ Wp,
                                                   const float* __restrict__ bias,
                                                   u16* __restrict__ Xout, int ostride,
                                                   float* __restrict__ outF) {
  const int lane = threadIdx.x & 63, wv = threadIdx.x >> 6;
  const int bi = blockIdx.x >> 9;
  const int h = (blockIdx.x >> 1) & 255;
  const int w0 = (blockIdx.x & 1) << 7;
  const int co0 = blockIdx.y * (MF * 16);
  const int l15 = lane & 15, klane = (lane >> 4) << 3;
  const int ncol0 = w0 + wv * 32 + l15;
  const int rowbase = (bi << 8) + h;

  const f32x4 zf = {0.f, 0.f, 0.f, 0.f};
  const short8 z8 = {0, 0, 0, 0, 0, 0, 0, 0};
  f32x4 acc[MF][2];
#pragma unroll
  for (int m = 0; m < MF; ++m) { acc[m][0] = zf; acc[m][1] = zf; }

#pragma unroll 1
  for (int chunk = 0; chunk < CI / 32; ++chunk) {
#pragma unroll
    for (int tap = 0; tap < KS * KS; ++tap) {
      const int dy = (KS == 3) ? tap / 3 - 1 : 0;
      const int dx = (KS == 3) ? tap % 3 - 1 : 0;
      const int hin = h + dy;
      if (KS == 3 && (unsigned)hin >= 256u) continue;
      short8 bf[2];
#pragma unroll
      for (int nf = 0; nf < 2; ++nf) {
        int win = ncol0 + nf * 16 + dx;
        short8 v = z8;
        if (KS == 1 || (unsigned)win < 256u)
          v = *(const short8*)(Xin + ((size_t)(((bi << 8) + hin) * 256 + win)) * CI
                               + chunk * 32 + klane);
        bf[nf] = v;
      }
#pragma unroll
      for (int m = 0; m < MF; ++m) {
        const short8 af = *(const short8*)(Wp + ((size_t)(tap * COP + co0 + m * 16 + l15)) * CI
                                           + chunk * 32 + klane);
        mfma16(af, bf[0], acc[m][0]);
        mfma16(af, bf[1], acc[m][1]);
      }
    }
  }
  asm volatile("s_nop 7\n\ts_nop 7");

  const int co_sub = (lane >> 4) << 2;
  const size_t pixrow = (size_t)rowbase << 8;
#pragma unroll
  for (int m = 0; m < MF; ++m) {
    const int co = co0 + m * 16 + co_sub;
#pragma unroll
    for (int nf = 0; nf < 2; ++nf) {
      const int w = ncol0 + nf * 16;
      f32x4 v = acc[m][nf];
      if constexpr (OBF) {
        float t[4];
#pragma unroll
        for (int r = 0; r < 4; ++r) {
          float x = v[r] + bias[co + r];
          if constexpr (LRELU) x = x > 0.f ? x : 0.1f * x;
          t[r] = x;
        }
        ushort4 u;
        u.x = rne_bf16(t[0]); u.y = rne_bf16(t[1]);
        u.z = rne_bf16(t[2]); u.w = rne_bf16(t[3]);
        *(ushort4*)(Xout + (pixrow + w) * (size_t)ostride + co) = u;
      }
      if constexpr (COF32 > 0) {
#pragma unroll
        for (int r = 0; r < 4; ++r) {
          int c = co + r;
          if (c < COF32) {
            float x = v[r] + bias[c];
            if constexpr (LRELU) x = x > 0.f ? x : 0.1f * x;
            outF[((((size_t)bi * COF32) + c) << 16) + (h << 8) + w] = x;
          }
        }
      }
    }
  }
}

// ---------------------------------------------------------------------------
extern "C" void kernel_launch(void* const* d_in, const int* in_sizes, int n_in,
                              void* d_out, int out_size, void* d_ws, size_t ws_size,
                              hipStream_t stream) {
  const float* feat0 = (const float*)d_in[0];
  const float* feat1 = (const float*)d_in[1];
  const float* lfeat = (const float*)d_in[2];
  const float* lflow = (const float*)d_in[3];
  const float* w1 = (const float*)d_in[4];  const float* b1 = (const float*)d_in[5];
  const float* w2 = (const float*)d_in[6];  const float* b2 = (const float*)d_in[7];
  const float* w3 = (const float*)d_in[8];  const float* b3 = (const float*)d_in[9];
  const float* w4 = (const float*)d_in[10]; const float* b4 = (const float*)d_in[11];
  const float* w5 = (const float*)d_in[12]; const float* b5 = (const float*)d_in[13];
  const float* w6 = (const float*)d_in[14]; const float* b6 = (const float*)d_in[15];

  u16* ws = (u16*)d_ws;
  u16* X1 = ws;
  u16* X2 = ws + 33554432;
  u16* X3 = ws;
  u16* X4 = ws + 33554432;
  u16* X5 = ws;
  u16* X6 = ws + 33554432;
  u16* w1p = ws + 54525952;      // [192][256]
  u16* w2p = w1p + 49152;        // [3][384][160]
  u16* w3p = w2p + 184320;       // [3][384][128]
  u16* w4p = w3p + 147456;       // [3][320][128]
  u16* w5p = w4p + 147456;       // [3][192][96]
  u16* w6p = w5p + 55296;        // [9][16][64] (old layout)
  float* bp = (float*)(w6p + 9216);  // 576 f32
  u16* zbuf = (u16*)(bp + 576);      // 128 zero bf16

  const float* bp1 = bp;
  const float* bp2 = bp + 160;
  const float* bp3 = bp + 288;
  const float* bp4 = bp + 416;
  const float* bp5 = bp + 512;

  float* flow = (float*)d_out;              // [2][4][256][256]
  float* xout = (float*)d_out + 524288;     // [2][64][256][256]

  prep1_kernel<<<192, 256, 0, stream>>>(w1, w1p);
  prep3s_kernel<128, 160, 128, 384, 160><<<720, 256, 0, stream>>>(w2, w2p);
  prep3s_kernel<112, 128, 128, 384, 128><<<576, 256, 0, stream>>>(w3, w3p);
  prep3s_kernel< 96, 112,  96, 320, 128><<<480, 256, 0, stream>>>(w4, w4p);
  prep3s_kernel< 64,  96,  64, 192,  96><<<216, 256, 0, stream>>>(w5, w5p);
  prep3_kernel<  4,  64,  16,  64><<< 36, 256, 0, stream>>>(w6, w6p);
  prep_bias_kernel<<<3, 256, 0, stream>>>(b1, b2, b3, b4, b5, bp, zbuf);

  corr2_kernel<<<1024, 256, 0, stream>>>(feat0, feat1, X1);
  concat_kernel<<<2048, 256, 0, stream>>>(feat0, feat1, lfeat, lflow, X1);

  // <CI, BM, APLN, KS, OSTRIDE, LRELU, OBF, COF32>
  convs_kernel<256, 160, 192, 1, 160, true, true,  0><<<1024, 256, 0, stream>>>(X1, w1p, bp1, zbuf, X2, nullptr);
  convs_kernel<160, 128, 384, 3, 128, true, true,  0><<<1024, 256, 0, stream>>>(X2, w2p, bp2, zbuf, X3, nullptr);
  convs_kernel<128, 128, 384, 3, 128, true, true,  0><<<1024, 256, 0, stream>>>(X3, w3p, bp3, zbuf, X4, nullptr);
  convs_kernel<128,  96, 320, 3,  96, true, true,  0><<<1024, 256, 0, stream>>>(X4, w4p, bp4, zbuf, X5, nullptr);
  convs_kernel< 96,  64, 192, 3,  64, true, true, 64><<<1024, 256, 0, stream>>>(X5, w5p, bp5, zbuf, X6, xout);
  conv_kernel< 64,  16, 1, 3, false, false, 4><<<dim3(1024, 1), 256, 0, stream>>>(X6, w6p, b6, nullptr, 0, flow);
}

// Round 5
// 303.089 us; speedup vs baseline: 3.7035x; 1.0895x over previous
//
#include <hip/hip_runtime.h>
#include <hip/hip_fp16.h>
#include <cstdint>
#include <cstddef>

// ---------------------------------------------------------------------------
// Optical-flow estimator head, MI355X bf16 MFMA implementation. Round 5:
// corr rewritten as software-pipelined (issue-early/write-late) f16-dot2
// kernel with double-buffered 12-ch window chunks; corr now also writes the
// f0/f1 concat channels (ch 0..95) so concat only handles lf/lfl (96..163).
// Convs unchanged from round 4 (merged-tap, XOR-swizzled LDS, XCD swizzle).
//
// X layout: NHWC bf16, [pix = b*65536 + h*256 + w][C_stride]
// conv1 K-order permuted: X1 = [feats 0..163 | volume 164..244 | zero 245..255]
// 3x3 weights packed [dy][APLN rows = dx*BM+co, padded][CI].
// ---------------------------------------------------------------------------

using short8 = __attribute__((ext_vector_type(8))) short;
using f32x4  = __attribute__((ext_vector_type(4))) float;
typedef unsigned short u16;

__device__ __forceinline__ u16 rne_bf16(float f) {
  unsigned u = __float_as_uint(f);
  u += 0x7FFFu + ((u >> 16) & 1u);   // round-to-nearest-even
  return (u16)(u >> 16);
}

__device__ __forceinline__ void mfma16(const short8& a, const short8& b, f32x4& c) {
  asm("v_mfma_f32_16x16x32_bf16 %0, %1, %2, %0" : "+v"(c) : "v"(a), "v"(b));
}

__device__ __forceinline__ unsigned pk_f16(float a, float b) {
  unsigned r;
  asm("v_cvt_pkrtz_f16_f32 %0, %1, %2" : "=v"(r) : "v"(a), "v"(b));
  return r;
}

__device__ __forceinline__ void dot2(float& acc, unsigned a, unsigned b) {
  asm("v_dot2_f32_f16 %0, %1, %2, %0" : "+v"(acc) : "v"(a), "v"(b));
}

// async global -> LDS, 16B per lane (wave-uniform LDS base, per-lane source)
__device__ __forceinline__ void gload16(const void* g, void* l) {
  __builtin_amdgcn_global_load_lds(
      (const __attribute__((address_space(1))) unsigned int*)g,
      (__attribute__((address_space(3))) unsigned int*)l, 16, 0, 0);
}

// ---------------------------------------------------------------------------
// Weight prep
// ---------------------------------------------------------------------------
__global__ __launch_bounds__(256) void prep1_kernel(const float* __restrict__ w1,
                                                    u16* __restrict__ w1p) {
  int idx = blockIdx.x * 256 + threadIdx.x;     // < 192*256
  int co = idx >> 8, cip = idx & 255;
  float v = 0.f;
  if (co < 160 && cip < 245) {
    int ci = (cip < 164) ? (cip + 81) : (cip - 164);
    v = w1[co * 245 + ci];
  }
  w1p[idx] = rne_bf16(v);
}

// 3x3 weights -> [dy][APLN][CIP] bf16, row = dx*BM + co
template<int CO, int CIr, int BM, int APLN, int CIP>
__global__ __launch_bounds__(256) void prep3s_kernel(const float* __restrict__ w,
                                                     u16* __restrict__ wp) {
  int idx = blockIdx.x * 256 + threadIdx.x;     // < 3*APLN*CIP
  int ci = idx % CIP; int rest = idx / CIP;
  int row = rest % APLN; int dyp = rest / APLN;
  int dx = row / BM, co = row % BM;
  float v = 0.f;
  if (dx < 3 && co < CO && ci < CIr)
    v = w[(co * CIr + ci) * 9 + dyp * 3 + dx];
  wp[idx] = rne_bf16(v);
}

// old flat layout for conv6: [tap][COP][CIP]
template<int CO, int CI, int COP, int CIP>
__global__ __launch_bounds__(256) void prep3_kernel(const float* __restrict__ w,
                                                    u16* __restrict__ wp) {
  int idx = blockIdx.x * 256 + threadIdx.x;     // < 9*COP*CIP
  int ci = idx % CIP; int rest = idx / CIP;
  int co = rest % COP; int tap = rest / COP;
  float v = 0.f;
  if (co < CO && ci < CI) v = w[(co * CI + ci) * 9 + tap];
  wp[idx] = rne_bf16(v);
}

__global__ __launch_bounds__(256) void prep_bias_kernel(const float* __restrict__ b1,
    const float* __restrict__ b2, const float* __restrict__ b3,
    const float* __restrict__ b4, const float* __restrict__ b5,
    float* __restrict__ bp, u16* __restrict__ zbuf) {
  int i = blockIdx.x * 256 + threadIdx.x;       // grid 3 blocks
  if (i < 128) zbuf[i] = 0;
  float v = 0.f;
  if (i < 160) v = b1[i];
  else if (i < 288) v = b2[i - 160];
  else if (i < 416) { int c = i - 288; v = (c < 112) ? b3[c] : 0.f; }
  else if (i < 512) v = b4[i - 416];
  else if (i < 576) v = b5[i - 512];
  else return;
  bp[i] = v;
}

// ---------------------------------------------------------------------------
// Correlation, round-5 design (software-pipelined).
// Block = (b, 2 rows, 64 cols); 1024 blocks, XCD-swizzled.
// 4 chunks of 12 ch; window [3cpp][10r][72c] uint2 (f16x4) double-buffered
// (2 x 17.3 KB). Per chunk: loads issued into regs BEFORE previous chunk's
// compute; one barrier per chunk. Also emits X1 ch 0..47 (f0 bf16) and
// 48..95 (f1 bf16 from the staged window).
// ---------------------------------------------------------------------------
template<int NDY>
__device__ __forceinline__ void corr_compute3(const uint2* __restrict__ wb,
                                              const unsigned* __restrict__ f0p,
                                              float* __restrict__ cv,
                                              int row, int col, int dy0) {
#pragma unroll
  for (int d = 0; d < NDY; ++d) {
    const int r = row + dy0 + d;
#pragma unroll
    for (int cpp = 0; cpp < 3; ++cpp) {
      const uint2* base = wb + (cpp * 10 + r) * 72 + col;
#pragma unroll
      for (int dx = 0; dx < 9; ++dx) {
        const uint2 v = base[dx];
        dot2(cv[d * 9 + dx], v.x, f0p[2 * cpp]);
        dot2(cv[d * 9 + dx], v.y, f0p[2 * cpp + 1]);
      }
    }
  }
}

__global__ __launch_bounds__(256) void corr3_kernel(const float* __restrict__ f0,
                                                    const float* __restrict__ f1,
                                                    u16* __restrict__ X1) {
  __shared__ uint2 win_s[2][2160];       // [3cpp][10r][72c] per buffer
  const int bid = blockIdx.x;
  const int swz = (bid & 7) * 128 + (bid >> 3);   // XCD-contiguous, bijective
  const int b = swz >> 9, rest = swz & 511;
  const int hp = rest >> 2, ct = rest & 3;
  const int h0 = hp << 1, w0 = ct << 6;
  const int tid = threadIdx.x, lane = tid & 63, wv = tid >> 6;
  const int half = wv >> 1, row = wv & 1, col = lane;

  // ---- per-thread slot descriptors (fixed across chunks) ----
  int slot_off[9];
  unsigned ok_mask = 0;
#pragma unroll
  for (int k = 0; k < 9; ++k) {
    int i = k * 256 + tid;
    bool act = i < 2160;
    int ii = act ? i : 0;
    int c = ii % 72, q = ii / 72;
    int r = q % 10, cpp = q / 10;
    int hin = h0 + r - 4, win = w0 + c - 4;
    bool ok = act && ((unsigned)hin < 256u) && ((unsigned)win < 256u);
    if (ok) ok_mask |= (1u << k);
    slot_off[k] = ((b * 48 + cpp * 4) << 16) + (hin << 8) + win;
  }
  const int pixoff = ((b * 48) << 16) + ((h0 + row) << 8) + (w0 + col);
  const size_t pix = ((size_t)b << 16) + ((size_t)(h0 + row) << 8) + (w0 + col);

  float sv[9][4];
  float f0v[12];
#pragma unroll
  for (int k = 0; k < 9; ++k)
#pragma unroll
    for (int j = 0; j < 4; ++j) sv[k][j] = 0.f;

  auto issue = [&](int cc) {
#pragma unroll
    for (int k = 0; k < 9; ++k) {
      if (ok_mask & (1u << k)) {
        const float* p = f1 + (size_t)(slot_off[k] + ((cc * 12) << 16));
#pragma unroll
        for (int j = 0; j < 4; ++j) sv[k][j] = p[(size_t)j << 16];
      }
    }
#pragma unroll
    for (int j = 0; j < 12; ++j)
      f0v[j] = f0[(size_t)(pixoff + ((cc * 12 + j) << 16))];
  };

  float cv[45];
#pragma unroll
  for (int t = 0; t < 45; ++t) cv[t] = 0.f;

  issue(0);
  int buf = 0;
#pragma unroll 1
  for (int cc = 0; cc < 4; ++cc) {
    // ---- consume f0v: f16 pairs for dot2 + bf16 store (ch cc*12..) ----
    unsigned f0p[6];
#pragma unroll
    for (int j = 0; j < 6; ++j) f0p[j] = pk_f16(f0v[2 * j], f0v[2 * j + 1]);
    {
      u16* dst0 = X1 + pix * 256 + cc * 12;
#pragma unroll
      for (int q = 0; q < 3; ++q) {
        uint2 u;
        u.x = (unsigned)rne_bf16(f0v[4 * q + 0]) | ((unsigned)rne_bf16(f0v[4 * q + 1]) << 16);
        u.y = (unsigned)rne_bf16(f0v[4 * q + 2]) | ((unsigned)rne_bf16(f0v[4 * q + 3]) << 16);
        *(uint2*)(dst0 + 4 * q) = u;
      }
    }
    // ---- window LDS write ----
    uint2* wb = &win_s[buf][0];
#pragma unroll
    for (int k = 0; k < 9; ++k)
      if (k * 256 + tid < 2160)
        wb[k * 256 + tid] = make_uint2(pk_f16(sv[k][0], sv[k][1]),
                                       pk_f16(sv[k][2], sv[k][3]));
    __syncthreads();
    if (cc < 3) issue(cc + 1);          // prefetch next chunk under compute
    // ---- own-pixel f1 bf16 from staged window (ch 48 + cc*12..) ----
    {
      const uint2* own = wb + (row + 4) * 72 + (col + 4);
      u16* dst1 = X1 + pix * 256 + 48 + cc * 12;
#pragma unroll
      for (int q = 0; q < 3; ++q) {
        uint2 v = own[q * 720];
        __half2 lo = *(__half2*)&v.x, hi = *(__half2*)&v.y;
        uint2 u;
        u.x = (unsigned)rne_bf16(__half2float(lo.x)) | ((unsigned)rne_bf16(__half2float(lo.y)) << 16);
        u.y = (unsigned)rne_bf16(__half2float(hi.x)) | ((unsigned)rne_bf16(__half2float(hi.y)) << 16);
        *(uint2*)(dst1 + 4 * q) = u;
      }
    }
    // ---- correlation compute ----
    if (half == 0) corr_compute3<4>(wb, f0p, cv, row, col, 0);
    else           corr_compute3<5>(wb, f0p, cv, row, col, 4);
    buf ^= 1;
  }

  // ---- scale, lrelu, bf16-pack, store cv ----
  u16* dst = X1 + pix * 256;
  const float sc = 1.0f / 48.0f;
  if (half == 0) {
    // taps 0..35 -> ch 164..199
#pragma unroll
    for (int qq = 0; qq < 9; ++qq) {
      u16 e[4];
#pragma unroll
      for (int j = 0; j < 4; ++j) {
        float v = cv[qq * 4 + j] * sc;
        v = v > 0.f ? v : 0.1f * v;
        e[j] = rne_bf16(v);
      }
      uint2 u;
      u.x = (unsigned)e[0] | ((unsigned)e[1] << 16);
      u.y = (unsigned)e[2] | ((unsigned)e[3] << 16);
      *(uint2*)(dst + 164 + qq * 4) = u;
    }
  } else {
    // taps 36..80 -> ch 200..244, zeros through 255
#pragma unroll
    for (int qq = 0; qq < 14; ++qq) {
      u16 e[4];
#pragma unroll
      for (int j = 0; j < 4; ++j) {
        int t = qq * 4 + j;
        float v = 0.f;
        if (t < 45) {
          v = cv[t] * sc;
          v = v > 0.f ? v : 0.1f * v;
        }
        e[j] = rne_bf16(v);
      }
      uint2 u;
      u.x = (unsigned)e[0] | ((unsigned)e[1] << 16);
      u.y = (unsigned)e[2] | ((unsigned)e[3] << 16);
      *(uint2*)(dst + 200 + qq * 4) = u;
    }
  }
}

// ---------------------------------------------------------------------------
// Concat (round 5: only last_feat/last_flow -> X1 ch 96..163).
// ---------------------------------------------------------------------------
__global__ __launch_bounds__(256) void concat68_kernel(const float* __restrict__ lf,
                                                       const float* __restrict__ lfl,
                                                       u16* __restrict__ X1) {
  __shared__ float s[16][68];
  const int t = threadIdx.x;
  const size_t px0 = (size_t)blockIdx.x * 64;
  const int b = blockIdx.x >> 10;
  const int hw0 = (blockIdx.x & 1023) * 64;

#pragma unroll 1
  for (int cc = 0; cc < 5; ++cc) {
    __syncthreads();
    {
      int px = t & 63, cg = t >> 6;
#pragma unroll
      for (int r = 0; r < 4; ++r) {
        int cl = cg * 4 + r;
        int c = cc * 16 + cl;           // 0..79 (68 used)
        int hw = hw0 + px;
        float v = 0.f;
        if (c < 64)       v = lf[(((size_t)(b * 64 + c)) << 16) + hw];
        else if (c < 68)  v = lfl[(((size_t)(b * 4 + (c - 64))) << 16) + hw];
        s[cl][px] = v;
      }
    }
    __syncthreads();
    {
      int px = t >> 2, g = t & 3;
      int cbase = cc * 16 + g * 4;
      if (cbase < 68) {
        ushort4 u;
        u.x = rne_bf16(s[g * 4 + 0][px]);
        u.y = rne_bf16(s[g * 4 + 1][px]);
        u.z = rne_bf16(s[g * 4 + 2][px]);
        u.w = rne_bf16(s[g * 4 + 3][px]);
        *(ushort4*)(X1 + (px0 + px) * 256 + 96 + cbase) = u;
      }
    }
  }
}

// ---------------------------------------------------------------------------
// Merged-tap LDS-staged implicit-GEMM conv (round-4 design, unchanged).
// ---------------------------------------------------------------------------
template<int CI, int BM, int APLN, int KS, int OSTRIDE, bool LRELU, bool OBF, int COF32>
__global__ __launch_bounds__(256) void convs_kernel(const u16* __restrict__ Xin,
    const u16* __restrict__ Wp, const float* __restrict__ bias,
    const u16* __restrict__ zbuf, u16* __restrict__ Xout,
    float* __restrict__ outF) {
  constexpr int NCH = CI / 32;
  constexpr int NDX = (KS == 3) ? 3 : 1;
  constexpr int AROUNDS = APLN / 64;
  constexpr int BROUNDS = (KS == 3) ? 3 : 2;
  constexpr int MF = BM / 32;
  constexpr int AELEMS = AROUNDS * 2048;
  constexpr int BPXMAX = (KS == 3) ? 132 : 128;
  __shared__ u16 lds[(AROUNDS + BROUNDS) * 2048];

  const int tid = threadIdx.x;
  const int lane = tid & 63, wv = tid >> 6;
  const int wm = wv >> 1, wn = wv & 1;
  const int bid = blockIdx.x;
  const int swz = (bid & 7) * 128 + (bid >> 3);
  const int bi = swz >> 9;
  const int h = (swz >> 1) & 255;
  const int w0 = (swz & 1) << 7;
  const int l15 = lane & 15, segr = lane >> 4;

  size_t aofs[AROUNDS];
#pragma unroll
  for (int r = 0; r < AROUNDS; ++r) {
    int slot = r * 256 + tid;
    int row = slot >> 2, sp = slot & 3;
    int seg = sp ^ ((row >> 1) & 3);
    aofs[r] = (size_t)row * CI + seg * 8;
  }
  size_t bofs[BROUNDS];
  bool bcolv[BROUNDS];
#pragma unroll
  for (int r = 0; r < BROUNDS; ++r) {
    int slot = r * 256 + tid;
    int pxl = slot >> 2, sp = slot & 3;
    int seg = sp ^ ((pxl >> 1) & 3);
    int px = (KS == 3) ? (w0 + pxl - 2) : (w0 + pxl);
    bcolv[r] = ((unsigned)px < 256u) && (pxl < BPXMAX);
    bofs[r] = (size_t)px * CI + seg * 8;
  }

  f32x4 acc[MF][4];
  const f32x4 zf = {0.f, 0.f, 0.f, 0.f};
#pragma unroll
  for (int m = 0; m < MF; ++m)
#pragma unroll
    for (int n = 0; n < 4; ++n) acc[m][n] = zf;

  int dy = 0, c = 0;
#pragma unroll 1
  for (int ph = 0; ph < NDX * NCH; ++ph) {
    __syncthreads();
    const u16* Wph = Wp + ((size_t)dy * APLN) * CI + c * 32;
#pragma unroll
    for (int r = 0; r < AROUNDS; ++r)
      gload16(Wph + aofs[r], &lds[r * 2048 + wv * 512]);
    const int hin = (KS == 3) ? (h + dy - 1) : h;
    const bool rv = (unsigned)hin < 256u;
    const u16* Brow = Xin + ((size_t)((bi << 8) + (rv ? hin : 0)) << 8) * CI + c * 32;
#pragma unroll
    for (int r = 0; r < BROUNDS; ++r) {
      const u16* src = (rv && bcolv[r]) ? (Brow + bofs[r]) : zbuf;
      gload16(src, &lds[AELEMS + r * 2048 + wv * 512]);
    }
    __syncthreads();

#pragma unroll
    for (int dx = 0; dx < NDX; ++dx) {
      short8 bfr[4];
#pragma unroll
      for (int n = 0; n < 4; ++n) {
        int p = wn * 64 + n * 16 + l15;
        int pxl = (KS == 3) ? (p + dx + 1) : p;
        int ba = (AELEMS * 2) + pxl * 64 + ((segr ^ ((pxl >> 1) & 3)) << 4);
        bfr[n] = *(const short8*)((const char*)lds + ba);
      }
      short8 afr[MF];
#pragma unroll
      for (int m = 0; m < MF; ++m) {
        int row = dx * BM + wm * (BM / 2) + m * 16 + l15;
        int aa = row * 64 + ((segr ^ ((row >> 1) & 3)) << 4);
        afr[m] = *(const short8*)((const char*)lds + aa);
      }
#pragma unroll
      for (int m = 0; m < MF; ++m)
#pragma unroll
        for (int n = 0; n < 4; ++n) mfma16(afr[m], bfr[n], acc[m][n]);
    }
    if (++c == NCH) { c = 0; ++dy; }
  }
  asm volatile("s_nop 7\n\ts_nop 7");

  const int co_sub = (lane >> 4) << 2;
  const size_t pixbase = ((size_t)((bi << 8) + h)) << 8;
#pragma unroll
  for (int m = 0; m < MF; ++m) {
    const int co = wm * (BM / 2) + m * 16 + co_sub;
#pragma unroll
    for (int n = 0; n < 4; ++n) {
      const int px = w0 + wn * 64 + n * 16 + l15;
      f32x4 v = acc[m][n];
      float t[4];
#pragma unroll
      for (int r = 0; r < 4; ++r) {
        float x = v[r] + bias[co + r];
        if (LRELU) x = x > 0.f ? x : 0.1f * x;
        t[r] = x;
      }
      if (OBF) {
        ushort4 u;
        u.x = rne_bf16(t[0]); u.y = rne_bf16(t[1]);
        u.z = rne_bf16(t[2]); u.w = rne_bf16(t[3]);
        *(ushort4*)(Xout + (pixbase + px) * OSTRIDE + co) = u;
      }
      if (COF32 > 0) {
#pragma unroll
        for (int r = 0; r < 4; ++r) {
          int cch = co + r;
          if (cch < COF32)
            outF[(((size_t)bi * COF32 + cch) << 16) + (h << 8) + px] = t[r];
        }
      }
    }
  }
}

// ---------------------------------------------------------------------------
// Old direct-global conv kernel for tiny conv6 (M=16, K=576).
// ---------------------------------------------------------------------------
template<int CI, int COP, int MF, int KS, bool LRELU, bool OBF, int COF32>
__global__ __launch_bounds__(256) void conv_kernel(const u16* __restrict__ Xin,
                                                   const u16* __restrict__ Wp,
                                                   const float* __restrict__ bias,
                                                   u16* __restrict__ Xout, int ostride,
                                                   float* __restrict__ outF) {
  const int lane = threadIdx.x & 63, wv = threadIdx.x >> 6;
  const int bi = blockIdx.x >> 9;
  const int h = (blockIdx.x >> 1) & 255;
  const int w0 = (blockIdx.x & 1) << 7;
  const int co0 = blockIdx.y * (MF * 16);
  const int l15 = lane & 15, klane = (lane >> 4) << 3;
  const int ncol0 = w0 + wv * 32 + l15;
  const int rowbase = (bi << 8) + h;

  const f32x4 zf = {0.f, 0.f, 0.f, 0.f};
  const short8 z8 = {0, 0, 0, 0, 0, 0, 0, 0};
  f32x4 acc[MF][2];
#pragma unroll
  for (int m = 0; m < MF; ++m) { acc[m][0] = zf; acc[m][1] = zf; }

#pragma unroll 1
  for (int chunk = 0; chunk < CI / 32; ++chunk) {
#pragma unroll
    for (int tap = 0; tap < KS * KS; ++tap) {
      const int dy = (KS == 3) ? tap / 3 - 1 : 0;
      const int dx = (KS == 3) ? tap % 3 - 1 : 0;
      const int hin = h + dy;
      if (KS == 3 && (unsigned)hin >= 256u) continue;
      short8 bf[2];
#pragma unroll
      for (int nf = 0; nf < 2; ++nf) {
        int win = ncol0 + nf * 16 + dx;
        short8 v = z8;
        if (KS == 1 || (unsigned)win < 256u)
          v = *(const short8*)(Xin + ((size_t)(((bi << 8) + hin) * 256 + win)) * CI
                               + chunk * 32 + klane);
        bf[nf] = v;
      }
#pragma unroll
      for (int m = 0; m < MF; ++m) {
        const short8 af = *(const short8*)(Wp + ((size_t)(tap * COP + co0 + m * 16 + l15)) * CI
                                           + chunk * 32 + klane);
        mfma16(af, bf[0], acc[m][0]);
        mfma16(af, bf[1], acc[m][1]);
      }
    }
  }
  asm volatile("s_nop 7\n\ts_nop 7");

  const int co_sub = (lane >> 4) << 2;
  const size_t pixrow = (size_t)rowbase << 8;
#pragma unroll
  for (int m = 0; m < MF; ++m) {
    const int co = co0 + m * 16 + co_sub;
#pragma unroll
    for (int nf = 0; nf < 2; ++nf) {
      const int w = ncol0 + nf * 16;
      f32x4 v = acc[m][nf];
      if constexpr (OBF) {
        float t[4];
#pragma unroll
        for (int r = 0; r < 4; ++r) {
          float x = v[r] + bias[co + r];
          if constexpr (LRELU) x = x > 0.f ? x : 0.1f * x;
          t[r] = x;
        }
        ushort4 u;
        u.x = rne_bf16(t[0]); u.y = rne_bf16(t[1]);
        u.z = rne_bf16(t[2]); u.w = rne_bf16(t[3]);
        *(ushort4*)(Xout + (pixrow + w) * (size_t)ostride + co) = u;
      }
      if constexpr (COF32 > 0) {
#pragma unroll
        for (int r = 0; r < 4; ++r) {
          int c = co + r;
          if (c < COF32) {
            float x = v[r] + bias[c];
            if constexpr (LRELU) x = x > 0.f ? x : 0.1f * x;
            outF[((((size_t)bi * COF32) + c) << 16) + (h << 8) + w] = x;
          }
        }
      }
    }
  }
}

// ---------------------------------------------------------------------------
extern "C" void kernel_launch(void* const* d_in, const int* in_sizes, int n_in,
                              void* d_out, int out_size, void* d_ws, size_t ws_size,
                              hipStream_t stream) {
  const float* feat0 = (const float*)d_in[0];
  const float* feat1 = (const float*)d_in[1];
  const float* lfeat = (const float*)d_in[2];
  const float* lflow = (const float*)d_in[3];
  const float* w1 = (const float*)d_in[4];  const float* b1 = (const float*)d_in[5];
  const float* w2 = (const float*)d_in[6];  const float* b2 = (const float*)d_in[7];
  const float* w3 = (const float*)d_in[8];  const float* b3 = (const float*)d_in[9];
  const float* w4 = (const float*)d_in[10]; const float* b4 = (const float*)d_in[11];
  const float* w5 = (const float*)d_in[12]; const float* b5 = (const float*)d_in[13];
  const float* w6 = (const float*)d_in[14]; const float* b6 = (const float*)d_in[15];

  u16* ws = (u16*)d_ws;
  u16* X1 = ws;
  u16* X2 = ws + 33554432;
  u16* X3 = ws;
  u16* X4 = ws + 33554432;
  u16* X5 = ws;
  u16* X6 = ws + 33554432;
  u16* w1p = ws + 54525952;      // [192][256]
  u16* w2p = w1p + 49152;        // [3][384][160]
  u16* w3p = w2p + 184320;       // [3][384][128]
  u16* w4p = w3p + 147456;       // [3][320][128]
  u16* w5p = w4p + 147456;       // [3][192][96]
  u16* w6p = w5p + 55296;        // [9][16][64] (old layout)
  float* bp = (float*)(w6p + 9216);  // 576 f32
  u16* zbuf = (u16*)(bp + 576);      // 128 zero bf16

  const float* bp1 = bp;
  const float* bp2 = bp + 160;
  const float* bp3 = bp + 288;
  const float* bp4 = bp + 416;
  const float* bp5 = bp + 512;

  float* flow = (float*)d_out;              // [2][4][256][256]
  float* xout = (float*)d_out + 524288;     // [2][64][256][256]

  prep1_kernel<<<192, 256, 0, stream>>>(w1, w1p);
  prep3s_kernel<128, 160, 128, 384, 160><<<720, 256, 0, stream>>>(w2, w2p);
  prep3s_kernel<112, 128, 128, 384, 128><<<576, 256, 0, stream>>>(w3, w3p);
  prep3s_kernel< 96, 112,  96, 320, 128><<<480, 256, 0, stream>>>(w4, w4p);
  prep3s_kernel< 64,  96,  64, 192,  96><<<216, 256, 0, stream>>>(w5, w5p);
  prep3_kernel<  4,  64,  16,  64><<< 36, 256, 0, stream>>>(w6, w6p);
  prep_bias_kernel<<<3, 256, 0, stream>>>(b1, b2, b3, b4, b5, bp, zbuf);

  corr3_kernel<<<1024, 256, 0, stream>>>(feat0, feat1, X1);
  concat68_kernel<<<2048, 256, 0, stream>>>(lfeat, lflow, X1);

  // <CI, BM, APLN, KS, OSTRIDE, LRELU, OBF, COF32>
  convs_kernel<256, 160, 192, 1, 160, true, true,  0><<<1024, 256, 0, stream>>>(X1, w1p, bp1, zbuf, X2, nullptr);
  convs_kernel<160, 128, 384, 3, 128, true, true,  0><<<1024, 256, 0, stream>>>(X2, w2p, bp2, zbuf, X3, nullptr);
  convs_kernel<128, 128, 384, 3, 128, true, true,  0><<<1024, 256, 0, stream>>>(X3, w3p, bp3, zbuf, X4, nullptr);
  convs_kernel<128,  96, 320, 3,  96, true, true,  0><<<1024, 256, 0, stream>>>(X4, w4p, bp4, zbuf, X5, nullptr);
  convs_kernel< 96,  64, 192, 3,  64, true, true, 64><<<1024, 256, 0, stream>>>(X5, w5p, bp5, zbuf, X6, xout);
  conv_kernel< 64,  16, 1, 3, false, false, 4><<<dim3(1024, 1), 256, 0, stream>>>(X6, w6p, b6, nullptr, 0, flow);
}